// Round 2
// baseline (567.582 us; speedup 1.0000x reference)
//
#include <hip/hip_runtime.h>
#include <cstdint>

// Problem constants (B, BS, M, D) = (64, 8, 512, 256), neg = B/BS = 8
#define NEG_FILL_F (-10000000000.0f)
constexpr int BB     = 64;
constexpr int BS_    = 8;
constexpr int MM     = 512;
constexpr int DD     = 256;
constexpr int ROWS_X = BB * MM;           // 32768
constexpr int ROWS_Y = BS_ * MM;          // 4096
constexpr int ROWS_ALL = ROWS_X + ROWS_Y; // 36864
// Triple-split k' = 768 slots, planar pairing:
//   slots [0,256):   A=h, B=h
//   slots [256,512): A=l, B=h
//   slots [512,768): A=h, B=l
// Storage is 512 shorts/row: [h-plane | l-plane]; the h-plane is read twice.
constexpr int KS     = 512;               // stored row length (shorts)

typedef __attribute__((ext_vector_type(8))) short short8;   // 8 bf16 = 4 VGPRs
typedef __attribute__((ext_vector_type(4))) float f32x4;    // MFMA C/D

__device__ inline unsigned short rne_bf16(float f) {
    unsigned int u = __float_as_uint(f);
    u = (u + 0x7FFFu + ((u >> 16) & 1u)) >> 16;
    return (unsigned short)u;
}
__device__ inline float bf2f(unsigned short h) {
    return __uint_as_float(((unsigned int)h) << 16);
}

__device__ inline f32x4 mfma16(short8 a, short8 b, f32x4 c) {
    return __builtin_amdgcn_mfma_f32_16x16x32_bf16(a, b, c, 0, 0, 0);
}

// Async global->LDS 16B copy. LDS dst is wave-uniform base; HW adds lane*16.
__device__ inline void gld16(const unsigned short* g, unsigned short* l) {
    __builtin_amdgcn_global_load_lds(
        (const __attribute__((address_space(1))) unsigned int*)g,
        (__attribute__((address_space(3))) unsigned int*)l, 16, 0, 0);
}

__device__ inline void mfma_4x4(const short8 af[4], const short8 bf_[4],
                                f32x4 acc[4][4]) {
    #pragma unroll
    for (int i = 0; i < 4; ++i)
        #pragma unroll
        for (int j = 0; j < 4; ++j)
            acc[i][j] = mfma16(af[i], bf_[j], acc[i][j]);
}

// ---------------------------------------------------------------------------
// Rot-swizzled planar staging of a 128-row x 96-slot tile from [h|l] storage
// (row stride KS=512 shorts). LDS row r chunk q holds global chunk
// cin = (q - r) mod 12 of the ck-th 96-slot window; planar mapping picks the
// h- or l-plane per chunk. ASIDE: A pairing (h,l,h); else B pairing (h,h,l).
// ---------------------------------------------------------------------------
template<bool ASIDE>
__device__ inline void stage_qk(unsigned short* dstbase,
                                const unsigned short* __restrict__ src,
                                int ck, int wave, int lane)
{
    #pragma unroll
    for (int s = 0; s < 6; ++s) {
        const int c  = s * 256 + wave * 64 + lane;  // 0..1535
        const int r  = c / 12;
        const int q  = c - r * 12;
        const int rm = r % 12;
        int cin = q - rm;
        cin += (cin >> 31) & 12;                    // (q - r) mod 12
        const int slotb = ck * 96 + cin * 8;        // global slot base 0..760
        const int p  = slotb >> 8;                  // plane index 0..2
        const int c8 = slotb & 255;                 // col within plane
        const int off = ASIDE ? ((p == 1) ? 256 : 0)
                              : ((p == 2) ? 256 : 0);
        gld16(src + (size_t)r * KS + off + c8,
              dstbase + (size_t)(s * 256 + wave * 64) * 8);
    }
}

// 4 A/B fragments from a rot-96 tile; rows rbase + {0,16,32,48} + lid.
// rm[i] = (rbase + i*16 + lid) % 12 precomputed by caller.
__device__ inline void frag4_rot96(const unsigned short (*T)[96], int rbase,
                                   int lid, const int rm[4], int c0,
                                   short8 f[4])
{
    #pragma unroll
    for (int i = 0; i < 4; ++i) {
        int q = c0 + rm[i];
        if (q >= 12) q -= 12;
        f[i] = *(const short8*)&T[rbase + i * 16 + lid][q * 8];
    }
}

// ---------------------------------------------------------------------------
// W -> Wb: [3][256][512] planar (h-plane | l-plane). 96 blocks x 256.
// ---------------------------------------------------------------------------
__global__ __launch_bounds__(256) void convw_kernel(
    const float* __restrict__ Wq, const float* __restrict__ Wk,
    const float* __restrict__ Wv, unsigned short* __restrict__ Wb)
{
    const int g  = blockIdx.x * 256 + threadIdx.x;   // < 24576
    const int e  = g * 8;                            // over 3*65536
    const int zi = e >> 16;
    const int off = e & 65535;
    const int row = off >> 8, k0 = off & 255;
    const float* W = (zi == 0) ? Wq : (zi == 1 ? Wk : Wv);
    float4 v0 = *(const float4*)(W + off);
    float4 v1 = *(const float4*)(W + off + 4);
    const float fv[8] = {v0.x, v0.y, v0.z, v0.w, v1.x, v1.y, v1.z, v1.w};
    short8 hh, ll;
    #pragma unroll
    for (int i = 0; i < 8; ++i) {
        unsigned short h = rne_bf16(fv[i]);
        hh[i] = (short)h;
        ll[i] = (short)rne_bf16(fv[i] - bf2f(h));
    }
    unsigned short* dst = Wb + (size_t)zi * 131072 + (size_t)row * KS;
    *(short8*)(dst + k0)       = hh;
    *(short8*)(dst + 256 + k0) = ll;
}

// ---------------------------------------------------------------------------
// Projections via MFMA (k'=768 planar). A split in-kernel from fp32 x|y;
// B async-staged from Wb. z=0 -> Qa, z=1 -> Kb (both [h|l] planar, 512/row);
// z=2 -> Vt[b][d][j] plain bf16.  grid = (288, 2, 3)
// ---------------------------------------------------------------------------
__global__ __launch_bounds__(256) void proj_kernel(
    const float* __restrict__ x, const float* __restrict__ y,
    const unsigned short* __restrict__ Wb,
    unsigned short* __restrict__ Qa, unsigned short* __restrict__ Kb,
    unsigned short* __restrict__ Vt)
{
    const int z    = blockIdx.z;
    const int row0 = blockIdx.x * 128;
    const int col0 = blockIdx.y * 128;
    const float* A = (row0 < ROWS_X) ? (x + (size_t)row0 * DD)
                                     : (y + (size_t)(row0 - ROWS_X) * DD);
    const unsigned short* Bsrc = Wb + (size_t)z * 131072 + (size_t)col0 * KS;

    __shared__ unsigned short Ab[128][96];
    __shared__ unsigned short Bb[128][96];

    const int t = threadIdx.x;
    const int wave = t >> 6, lane = t & 63, quad = lane >> 4, lid = lane & 15;
    const int wrow = (wave & 1) * 64, wcol = (wave >> 1) * 64;

    int rma[4], rmb[4];
    #pragma unroll
    for (int i = 0; i < 4; ++i) {
        rma[i] = (wrow + i * 16 + lid) % 12;
        rmb[i] = (wcol + i * 16 + lid) % 12;
    }

    f32x4 acc[4][4];
    #pragma unroll
    for (int i = 0; i < 4; ++i)
        #pragma unroll
        for (int j = 0; j < 4; ++j) acc[i][j] = (f32x4){0.f, 0.f, 0.f, 0.f};

    for (int ck = 0; ck < 8; ++ck) {
        // B async planar-rot
        stage_qk<false>(&Bb[0][0], Bsrc, ck, wave, lane);
        // A manual planar-rot split from fp32
        #pragma unroll
        for (int s = 0; s < 6; ++s) {
            const int c  = s * 256 + t;             // 0..1535
            const int r  = c / 12;
            const int q  = c - r * 12;
            const int rm = r % 12;
            int cin = q - rm;
            cin += (cin >> 31) & 12;
            const int slotb = ck * 96 + cin * 8;
            const int p  = slotb >> 8;
            const int c8 = slotb & 255;
            const float* ap = A + (size_t)r * DD + c8;
            float4 v0 = *(const float4*)ap;
            float4 v1 = *(const float4*)(ap + 4);
            const float fv[8] = {v0.x, v0.y, v0.z, v0.w, v1.x, v1.y, v1.z, v1.w};
            short8 o;
            if (p == 1) {
                #pragma unroll
                for (int e = 0; e < 8; ++e) {
                    unsigned short h = rne_bf16(fv[e]);
                    o[e] = (short)rne_bf16(fv[e] - bf2f(h));
                }
            } else {
                #pragma unroll
                for (int e = 0; e < 8; ++e) o[e] = (short)rne_bf16(fv[e]);
            }
            *(short8*)&Ab[r][q * 8] = o;
        }
        __syncthreads();
        #pragma unroll
        for (int kk = 0; kk < 96; kk += 32) {
            const int c0 = (kk >> 3) + quad;
            short8 af[4], bf_[4];
            frag4_rot96(Ab, wrow, lid, rma, c0, af);
            frag4_rot96(Bb, wcol, lid, rmb, c0, bf_);
            mfma_4x4(af, bf_, acc);
        }
        __syncthreads();
    }

    if (z == 2) {
        #pragma unroll
        for (int i = 0; i < 4; ++i) {
            const int rg = row0 + wrow + i * 16 + quad * 4;
            const int b  = rg >> 9;
            const int j  = rg & 511;
            #pragma unroll
            for (int jt = 0; jt < 4; ++jt) {
                const int col = col0 + wcol + jt * 16 + lid;
                *(ushort4*)(Vt + (size_t)b * DD * MM + (size_t)col * MM + j) =
                    make_ushort4(rne_bf16(acc[i][jt][0]), rne_bf16(acc[i][jt][1]),
                                 rne_bf16(acc[i][jt][2]), rne_bf16(acc[i][jt][3]));
            }
        }
    } else {
        unsigned short* dst = (z == 0) ? Qa : Kb;
        #pragma unroll
        for (int i = 0; i < 4; ++i) {
            const int rg = row0 + wrow + i * 16 + quad * 4;
            #pragma unroll
            for (int r = 0; r < 4; ++r) {
                unsigned short* rowp = dst + (size_t)(rg + r) * KS;
                #pragma unroll
                for (int jt = 0; jt < 4; ++jt) {
                    const int col = col0 + wcol + jt * 16 + lid;
                    const float v = acc[i][jt][r];
                    unsigned short h = rne_bf16(v);
                    rowp[col]       = h;                          // h-plane
                    rowp[256 + col] = rne_bf16(v - bf2f(h));      // l-plane
                }
            }
        }
    }
}

// ---------------------------------------------------------------------------
// Self scores (x-self z<64, y-self z>=64) via MFMA k'=768 planar, rot-swizzled
// staging, mask epilogue + fused per-block softmax partials. grid = (4,4,72)
// ---------------------------------------------------------------------------
__global__ __launch_bounds__(256) void scores_self_kernel(
    const unsigned short* __restrict__ Qa,
    const unsigned short* __restrict__ Kb,
    const int* __restrict__ mask_x, const int* __restrict__ mask_y,
    float* __restrict__ Sbase, float2* __restrict__ pstats)
{
    const int z    = blockIdx.z;                     // 0..71
    const int row0 = blockIdx.x * 128;
    const int col0 = blockIdx.y * 128;
    const unsigned short* Asrc = Qa + (size_t)(z * MM + row0) * KS;
    const unsigned short* Bsrc = Kb + (size_t)(z * MM + col0) * KS;
    const int* msk = (z < 64) ? (mask_x + z * MM) : (mask_y + (z - 64) * MM);
    float* S = Sbase + (size_t)z * MM * MM;

    __shared__ unsigned short Ab[128][96];
    __shared__ unsigned short Bb[128][96];
    __shared__ float pm2[128][2];
    __shared__ float ps2[128][2];

    const int t = threadIdx.x;
    const int wave = t >> 6, lane = t & 63, quad = lane >> 4, lid = lane & 15;
    const int wrow = (wave & 1) * 64, wcol = (wave >> 1) * 64;

    int rma[4], rmb[4];
    #pragma unroll
    for (int i = 0; i < 4; ++i) {
        rma[i] = (wrow + i * 16 + lid) % 12;
        rmb[i] = (wcol + i * 16 + lid) % 12;
    }

    f32x4 acc[4][4];
    #pragma unroll
    for (int i = 0; i < 4; ++i)
        #pragma unroll
        for (int j = 0; j < 4; ++j) acc[i][j] = (f32x4){0.f, 0.f, 0.f, 0.f};

    for (int ck = 0; ck < 8; ++ck) {
        stage_qk<true >(&Ab[0][0], Asrc, ck, wave, lane);
        stage_qk<false>(&Bb[0][0], Bsrc, ck, wave, lane);
        __syncthreads();
        #pragma unroll
        for (int kk = 0; kk < 96; kk += 32) {
            const int c0 = (kk >> 3) + quad;
            short8 af[4], bf_[4];
            frag4_rot96(Ab, wrow, lid, rma, c0, af);
            frag4_rot96(Bb, wcol, lid, rmb, c0, bf_);
            mfma_4x4(af, bf_, acc);
        }
        __syncthreads();
    }

    int mcol[4];
    #pragma unroll
    for (int jt = 0; jt < 4; ++jt) mcol[jt] = msk[col0 + wcol + jt * 16 + lid];

    #pragma unroll
    for (int i = 0; i < 4; ++i) {
        const int rl0 = wrow + i * 16 + quad * 4;
        #pragma unroll
        for (int r = 0; r < 4; ++r) {
            const int rlocal = rl0 + r;
            const int rg = row0 + rlocal;
            const bool mr = (msk[rg] != 0);
            float* Srow = S + (size_t)rg * MM;
            float v[4];
            float mt = -3.4e38f;
            #pragma unroll
            for (int jt = 0; jt < 4; ++jt) {
                const int col = col0 + wcol + jt * 16 + lid;
                const bool valid = mr && (mcol[jt] != 0);
                v[jt] = valid ? acc[i][jt][r] : NEG_FILL_F;
                Srow[col] = v[jt];
                mt = fmaxf(mt, v[jt]);
            }
            #pragma unroll
            for (int o = 1; o < 16; o <<= 1) mt = fmaxf(mt, __shfl_xor(mt, o));
            float se = 0.f;
            #pragma unroll
            for (int jt = 0; jt < 4; ++jt) se += __expf(v[jt] - mt);
            #pragma unroll
            for (int o = 1; o < 16; o <<= 1) se += __shfl_xor(se, o);
            if (lid == 0) { pm2[rlocal][wave >> 1] = mt; ps2[rlocal][wave >> 1] = se; }
        }
    }
    __syncthreads();
    if (t < 128) {
        const float m0 = pm2[t][0], m1 = pm2[t][1];
        const float mm = fmaxf(m0, m1);
        const float ss = ps2[t][0] * __expf(m0 - mm) + ps2[t][1] * __expf(m1 - mm);
        pstats[(size_t)(z * 4 + blockIdx.y) * MM + row0 + t] = make_float2(mm, ss);
    }
}

// ---------------------------------------------------------------------------
// Cross scores (xy) in single bf16, K=256 (feeds softmax only). Reads the
// h-plane of Qa/Kb directly (plain bf16 projections, stride KS). XOR-swizzled
// 64-wide tiles (2-way, free). grid = (4, 4, 64)
// ---------------------------------------------------------------------------
__global__ __launch_bounds__(256) void scores_xy_kernel(
    const unsigned short* __restrict__ Qa, const unsigned short* __restrict__ Kb,
    const int* __restrict__ mask_x, const int* __restrict__ mask_y,
    float* __restrict__ Sbase, float* __restrict__ Mbase,
    float2* __restrict__ pstats)
{
    const int z = blockIdx.z;                        // 0..63
    const int n = z >> 3, s = z & 7;
    const int bq = s * 8 + n;                        // x batch
    const int bk = s;                                // y batch (rows 32768+)
    const int row0 = blockIdx.x * 128;
    const int col0 = blockIdx.y * 128;
    const unsigned short* Asrc = Qa + (size_t)(bq * MM + row0) * KS;
    const unsigned short* Bsrc = Kb + (size_t)((ROWS_X + bk * MM) + col0) * KS;
    const int* mq = mask_x + bq * MM;
    const int* mk = mask_y + bk * MM;
    float* Sl = Sbase + (size_t)z * MM * MM;
    float* Ml = Mbase + (size_t)z * MM * MM;

    __shared__ unsigned short Ab[128][64];
    __shared__ unsigned short Bb[128][64];
    __shared__ float pm2[128][2];
    __shared__ float ps2[128][2];

    const int t = threadIdx.x;
    const int wave = t >> 6, lane = t & 63, quad = lane >> 4, lid = lane & 15;
    const int wrow = (wave & 1) * 64, wcol = (wave >> 1) * 64;
    const int x7 = lid & 7;

    f32x4 acc[4][4];
    #pragma unroll
    for (int i = 0; i < 4; ++i)
        #pragma unroll
        for (int j = 0; j < 4; ++j) acc[i][j] = (f32x4){0.f, 0.f, 0.f, 0.f};

    for (int ck = 0; ck < 4; ++ck) {
        #pragma unroll
        for (int s4 = 0; s4 < 4; ++s4) {
            const int c   = s4 * 256 + wave * 64 + lane;  // 0..1023
            const int r   = c >> 3;
            const int cin = (c & 7) ^ (r & 7);
            gld16(Asrc + (size_t)r * KS + ck * 64 + cin * 8,
                  &Ab[0][0] + (size_t)(s4 * 256 + wave * 64) * 8);
        }
        #pragma unroll
        for (int s4 = 0; s4 < 4; ++s4) {
            const int c   = s4 * 256 + wave * 64 + lane;
            const int r   = c >> 3;
            const int cin = (c & 7) ^ (r & 7);
            gld16(Bsrc + (size_t)r * KS + ck * 64 + cin * 8,
                  &Bb[0][0] + (size_t)(s4 * 256 + wave * 64) * 8);
        }
        __syncthreads();
        #pragma unroll
        for (int kk = 0; kk < 64; kk += 32) {
            const int c0 = (kk >> 3) + quad;
            const int q  = c0 ^ x7;
            short8 af[4], bf_[4];
            #pragma unroll
            for (int i = 0; i < 4; ++i) {
                af[i]  = *(const short8*)&Ab[wrow + i * 16 + lid][q * 8];
                bf_[i] = *(const short8*)&Bb[wcol + i * 16 + lid][q * 8];
            }
            mfma_4x4(af, bf_, acc);
        }
        __syncthreads();
    }

    int mcol[4];
    #pragma unroll
    for (int jt = 0; jt < 4; ++jt) mcol[jt] = mk[col0 + wcol + jt * 16 + lid];

    #pragma unroll
    for (int i = 0; i < 4; ++i) {
        const int rl0 = wrow + i * 16 + quad * 4;
        #pragma unroll
        for (int r = 0; r < 4; ++r) {
            const int rlocal = rl0 + r;
            const int rg = row0 + rlocal;
            const bool mr = (mq[rg] != 0);
            float* Srow = Sl + (size_t)rg * MM;
            float* Mrow = Ml + (size_t)rg * MM;
            float v[4];
            float mt = -3.4e38f;
            #pragma unroll
            for (int jt = 0; jt < 4; ++jt) {
                const int col = col0 + wcol + jt * 16 + lid;
                const bool valid = mr && (mcol[jt] != 0);
                v[jt] = valid ? acc[i][jt][r] : NEG_FILL_F;
                Srow[col] = v[jt];
                Mrow[col] = valid ? 1.0f : 0.0f;
                mt = fmaxf(mt, v[jt]);
            }
            #pragma unroll
            for (int o = 1; o < 16; o <<= 1) mt = fmaxf(mt, __shfl_xor(mt, o));
            float se = 0.f;
            #pragma unroll
            for (int jt = 0; jt < 4; ++jt) se += __expf(v[jt] - mt);
            #pragma unroll
            for (int o = 1; o < 16; o <<= 1) se += __shfl_xor(se, o);
            if (lid == 0) { pm2[rlocal][wave >> 1] = mt; ps2[rlocal][wave >> 1] = se; }
        }
    }
    __syncthreads();
    if (t < 128) {
        const float m0 = pm2[t][0], m1 = pm2[t][1];
        const float mm = fmaxf(m0, m1);
        const float ss = ps2[t][0] * __expf(m0 - mm) + ps2[t][1] * __expf(m1 - mm);
        pstats[(size_t)(z * 4 + blockIdx.y) * MM + row0 + t] = make_float2(mm, ss);
    }
}

// ---------------------------------------------------------------------------
// Merge 4 col-block partials per row -> (max, 1/sum). grid = 69632/256 = 272.
// ---------------------------------------------------------------------------
__global__ __launch_bounds__(256) void reduce4_kernel(
    const float2* __restrict__ p, float2* __restrict__ st)
{
    const int row = blockIdx.x * 256 + threadIdx.x;
    const int z = row >> 9, rl = row & 511;
    float m = -3.4e38f, s = 0.f;
    #pragma unroll
    for (int by = 0; by < 4; ++by) {
        float2 v = p[(size_t)(z * 4 + by) * MM + rl];
        float nm = fmaxf(m, v.x);
        s = s * __expf(m - nm) + v.y * __expf(v.x - nm);
        m = nm;
    }
    st[row] = make_float2(m, 1.0f / s);
}

// ---------------------------------------------------------------------------
// Context via MFMA (plain bf16, K'=512). A = exp(S-m) manual-staged into an
// XOR-swizzled [128][64] tile (was [128][72]: 144B stride = 8-way conflict on
// ds_read_b128); B = Vt async-copied XOR-swizzled. grid = (4, 2, 72)
// ---------------------------------------------------------------------------
__global__ __launch_bounds__(256) void ctx_kernel(
    const float* __restrict__ Sbase, const float2* __restrict__ stats,
    const unsigned short* __restrict__ Vt_base, float* __restrict__ Obase)
{
    const int b = blockIdx.z;
    const float*          S  = Sbase + (size_t)b * MM * MM;
    const float2*         st = stats + (size_t)b * MM;
    const unsigned short* Vt = Vt_base + (size_t)b * DD * MM;
    float*                O  = Obase + (size_t)b * MM * DD;

    const int row0 = blockIdx.x * 128;
    const int col0 = blockIdx.y * 128;

    __shared__ unsigned short Ab[128][64];
    __shared__ unsigned short Bb[128][64];

    const int t = threadIdx.x;
    const int wave = t >> 6, lane = t & 63, quad = lane >> 4, lid = lane & 15;
    const int wrow = (wave & 1) * 64, wcol = (wave >> 1) * 64;
    const int x7 = lid & 7;

    f32x4 acc[4][4];
    #pragma unroll
    for (int i = 0; i < 4; ++i)
        #pragma unroll
        for (int j = 0; j < 4; ++j) acc[i][j] = (f32x4){0.f, 0.f, 0.f, 0.f};

    for (int ck = 0; ck < 8; ++ck) {
        // B: Vt rows are d (output cols); XOR-swizzled source chunks
        #pragma unroll
        for (int s4 = 0; s4 < 4; ++s4) {
            const int c   = s4 * 256 + wave * 64 + lane;  // 0..1023
            const int r   = c >> 3;
            const int cin = (c & 7) ^ (r & 7);
            gld16(Vt + (size_t)(col0 + r) * MM + ck * 64 + cin * 8,
                  &Bb[0][0] + (size_t)(s4 * 256 + wave * 64) * 8);
        }
        // A: exp(S - m) -> bf16, manual, XOR-swizzled LDS slot
        #pragma unroll
        for (int s4 = 0; s4 < 4; ++s4) {
            const int c    = s4 * 256 + t;     // 0..1023
            const int row  = c >> 3;
            const int j8   = (c & 7) * 8;      // source col group (unswizzled)
            const int slot = (c & 7) ^ (row & 7);
            const float* sp = S + (size_t)(row0 + row) * MM + ck * 64 + j8;
            float4 v0 = *(const float4*)sp;
            float4 v1 = *(const float4*)(sp + 4);
            const float pm = st[row0 + row].x;
            short8 pk;
            pk[0] = (short)rne_bf16(__expf(v0.x - pm));
            pk[1] = (short)rne_bf16(__expf(v0.y - pm));
            pk[2] = (short)rne_bf16(__expf(v0.z - pm));
            pk[3] = (short)rne_bf16(__expf(v0.w - pm));
            pk[4] = (short)rne_bf16(__expf(v1.x - pm));
            pk[5] = (short)rne_bf16(__expf(v1.y - pm));
            pk[6] = (short)rne_bf16(__expf(v1.z - pm));
            pk[7] = (short)rne_bf16(__expf(v1.w - pm));
            *(short8*)&Ab[row][slot * 8] = pk;
        }
        __syncthreads();
        #pragma unroll
        for (int kk = 0; kk < 64; kk += 32) {
            const int c0 = (kk >> 3) + quad;
            const int q  = c0 ^ x7;
            short8 af[4], bf_[4];
            #pragma unroll
            for (int i = 0; i < 4; ++i) {
                af[i]  = *(const short8*)&Ab[wrow + i * 16 + lid][q * 8];
                bf_[i] = *(const short8*)&Bb[wcol + i * 16 + lid][q * 8];
            }
            mfma_4x4(af, bf_, acc);
        }
        __syncthreads();
    }

    #pragma unroll
    for (int i = 0; i < 4; ++i) {
        const int rgb = row0 + wrow + i * 16 + quad * 4;
        float inv[4];
        #pragma unroll
        for (int r = 0; r < 4; ++r) inv[r] = st[rgb + r].y;
        #pragma unroll
        for (int jt = 0; jt < 4; ++jt) {
            const int col = col0 + wcol + jt * 16 + lid;
            #pragma unroll
            for (int r = 0; r < 4; ++r)
                O[(size_t)(rgb + r) * DD + col] = acc[i][jt][r] * inv[r];
        }
    }
}

// ---------------------------------------------------------------------------
// In-place softmax transform of the scores_xy slot -> probs_xy.
// ---------------------------------------------------------------------------
__global__ __launch_bounds__(128) void softmax_apply(
    float* __restrict__ S, const float2* __restrict__ stats)
{
    const int row = blockIdx.x;
    const float2 st = stats[row];
    float4* r = (float4*)(S + (size_t)row * MM) + threadIdx.x;
    float4 v = *r;
    v.x = __expf(v.x - st.x) * st.y;
    v.y = __expf(v.y - st.x) * st.y;
    v.z = __expf(v.z - st.x) * st.y;
    v.w = __expf(v.w - st.x) * st.y;
    *r = v;
}

// ---------------------------------------------------------------------------
// y_len: one block per s, 64-lane reduce of mask_y[s,:]; lane n<8 writes n*8+s.
// ---------------------------------------------------------------------------
__global__ void ylen_kernel(const int* __restrict__ mask_y, float* __restrict__ out)
{
    const int s = blockIdx.x;
    const int lane = threadIdx.x;
    int c = 0;
    #pragma unroll
    for (int k = 0; k < 8; ++k) c += (mask_y[s * MM + k * 64 + lane] != 0);
    #pragma unroll
    for (int off = 32; off; off >>= 1) c += __shfl_xor(c, off);
    if (lane < 8) out[lane * 8 + s] = (float)c;
}

// ---------------------------------------------------------------------------
extern "C" void kernel_launch(void* const* d_in, const int* in_sizes, int n_in,
                              void* d_out, int out_size, void* d_ws, size_t ws_size,
                              hipStream_t stream)
{
    const float* x      = (const float*)d_in[0];
    const float* y      = (const float*)d_in[1];
    const int*   mask_x = (const int*)d_in[2];
    const int*   mask_y = (const int*)d_in[3];
    const float* Wq     = (const float*)d_in[4];
    const float* Wk     = (const float*)d_in[5];
    const float* Wv     = (const float*)d_in[6];
    float* out = (float*)d_out;

    // Workspace (~96 MB): Wb | Qa | Kb | Vt | stats | pstats
    unsigned short* Wb = (unsigned short*)d_ws;            // 3*256*512   = 393216
    unsigned short* Qa = Wb + 393216;                      // 36864*512   = 18874368
    unsigned short* Kb = Qa + 18874368;
    unsigned short* Vt = Kb + 18874368;                    // 72*256*512  = 9437184
    float2* stats_x  = (float2*)(Vt + 9437184);            // 69632 rows contiguous
    float2* stats_xy = stats_x + ROWS_ALL;
    float2* ps_x  = stats_x + (ROWS_ALL + ROWS_X);         // 72 z then 64 z
    float2* ps_xy = ps_x + (64 + 8) * 4 * 512;

    // Output slots (floats, concatenated in reference return order)
    float* out_ctx_x = out;                 // 64*512*256   = 8388608 (+ctx_y)
    float* out_sx    = out + 9437184;       // 64*512*512   = 16777216 (+sy)
    float* out_pxy   = out + 28311552;      // 8*8*512*512  = 16777216
    float* out_mxy   = out + 45088768;      // 8*8*512*512  = 16777216
    float* out_ylen  = out + 61865984;      // 8*8          = 64

    // 1. W -> planar split; y_len (independent, tiny)
    convw_kernel<<<96, 256, 0, stream>>>(Wq, Wk, Wv, Wb);
    ylen_kernel<<<8, 64, 0, stream>>>(mask_y, out_ylen);

    // 2. Projections (MFMA): Qa/Kb planar [h|l], Vt transposed bf16
    proj_kernel<<<dim3(288, 2, 3), 256, 0, stream>>>(x, y, Wb, Qa, Kb, Vt);

    // 3. Scores: self (x+y merged, triple-split) and xy (h-plane bf16, K=256)
    scores_self_kernel<<<dim3(4, 4, 72), 256, 0, stream>>>(
        Qa, Kb, mask_x, mask_y, out_sx, ps_x);
    scores_xy_kernel<<<dim3(4, 4, 64), 256, 0, stream>>>(
        Qa, Kb, mask_x, mask_y, out_pxy, out_mxy, ps_xy);

    // 4. Merge partials -> (max, 1/sum) for all 69632 rows
    reduce4_kernel<<<(ROWS_ALL + ROWS_X) / 256, 256, 0, stream>>>(ps_x, stats_x);

    // 5. scores_xy -> probs_xy in place (pxy still LLC-warm)
    softmax_apply<<<ROWS_X, 128, 0, stream>>>(out_pxy, stats_xy);

    // 6. Context GEMMs (x+y merged; exp fused on A-stage)
    ctx_kernel<<<dim3(4, 2, 72), 256, 0, stream>>>(out_sx, stats_x, Vt, out_ctx_x);
}

// Round 3
// 516.784 us; speedup vs baseline: 1.0983x; 1.0983x over previous
//
#include <hip/hip_runtime.h>
#include <cstdint>

// Problem constants (B, BS, M, D) = (64, 8, 512, 256), neg = B/BS = 8
#define NEG_FILL_F (-10000000000.0f)
constexpr int BB     = 64;
constexpr int BS_    = 8;
constexpr int MM     = 512;
constexpr int DD     = 256;
constexpr int ROWS_X = BB * MM;           // 32768
constexpr int ROWS_Y = BS_ * MM;          // 4096
constexpr int ROWS_ALL = ROWS_X + ROWS_Y; // 36864
// Triple-split k' = 768 slots, planar pairing:
//   slots [0,256):   A=h, B=h
//   slots [256,512): A=l, B=h
//   slots [512,768): A=h, B=l
// Storage is 512 shorts/row: [h-plane | l-plane]; the h-plane is read twice.
// K-loop runs twelve 64-slot windows; window w lives entirely in one plane.
constexpr int KS     = 512;               // stored row length (shorts)

typedef __attribute__((ext_vector_type(8))) short short8;   // 8 bf16 = 4 VGPRs
typedef __attribute__((ext_vector_type(4))) float f32x4;    // MFMA C/D

__device__ inline unsigned short rne_bf16(float f) {
    unsigned int u = __float_as_uint(f);
    u = (u + 0x7FFFu + ((u >> 16) & 1u)) >> 16;
    return (unsigned short)u;
}
__device__ inline float bf2f(unsigned short h) {
    return __uint_as_float(((unsigned int)h) << 16);
}

__device__ inline f32x4 mfma16(short8 a, short8 b, f32x4 c) {
    return __builtin_amdgcn_mfma_f32_16x16x32_bf16(a, b, c, 0, 0, 0);
}

// Async global->LDS 16B copy. LDS dst is wave-uniform base; HW adds lane*16.
__device__ inline void gld16(const unsigned short* g, unsigned short* l) {
    __builtin_amdgcn_global_load_lds(
        (const __attribute__((address_space(1))) unsigned int*)g,
        (__attribute__((address_space(3))) unsigned int*)l, 16, 0, 0);
}

__device__ inline void mfma_4x4(const short8 af[4], const short8 bf_[4],
                                f32x4 acc[4][4]) {
    #pragma unroll
    for (int i = 0; i < 4; ++i)
        #pragma unroll
        for (int j = 0; j < 4; ++j)
            acc[i][j] = mfma16(af[i], bf_[j], acc[i][j]);
}

// Window -> column base within the planar [h|l] row (shorts).
// A pairing (h,l,h): plane 1 is the l-plane. B pairing (h,h,l): plane 2 is l.
__device__ inline int awin(int w) { return ((((w >> 2) == 1) ? 256 : 0) + (w & 3) * 64); }
__device__ inline int bwin(int w) { return ((((w >> 2) == 2) ? 256 : 0) + (w & 3) * 64); }

// Stage one [128][64] bf16 tile, XOR-swizzled (exact 2-way = free), async.
// srccol = absolute short offset within the row (plane offset included).
__device__ inline void stage64(unsigned short* dstbase,
                               const unsigned short* __restrict__ src,
                               int srccol, int wave, int lane)
{
    #pragma unroll
    for (int s4 = 0; s4 < 4; ++s4) {
        const int c   = s4 * 256 + wave * 64 + lane;  // 0..1023
        const int r   = c >> 3;
        const int cin = (c & 7) ^ (r & 7);
        gld16(src + (size_t)r * KS + srccol + cin * 8,
              dstbase + (size_t)(s4 * 256 + wave * 64) * 8);
    }
}

// 4 fragments, rows rbase+{0,16,32,48}+lid, from a [128][64] XOR tile.
// row&7 == lid&7 for all four, so one q serves all.
__device__ inline void frag4_x64(const unsigned short (*T)[64], int rbase,
                                 int lid, int c0, short8 f[4])
{
    const int q = c0 ^ (lid & 7);
    #pragma unroll
    for (int i = 0; i < 4; ++i)
        f[i] = *(const short8*)&T[rbase + i * 16 + lid][q * 8];
}

// ---------------------------------------------------------------------------
// W -> Wb: [3][256][512] planar (h-plane | l-plane). 96 blocks x 256.
// ---------------------------------------------------------------------------
__global__ __launch_bounds__(256) void convw_kernel(
    const float* __restrict__ Wq, const float* __restrict__ Wk,
    const float* __restrict__ Wv, unsigned short* __restrict__ Wb)
{
    const int g  = blockIdx.x * 256 + threadIdx.x;   // < 24576
    const int e  = g * 8;                            // over 3*65536
    const int zi = e >> 16;
    const int off = e & 65535;
    const int row = off >> 8, k0 = off & 255;
    const float* W = (zi == 0) ? Wq : (zi == 1 ? Wk : Wv);
    float4 v0 = *(const float4*)(W + off);
    float4 v1 = *(const float4*)(W + off + 4);
    const float fv[8] = {v0.x, v0.y, v0.z, v0.w, v1.x, v1.y, v1.z, v1.w};
    short8 hh, ll;
    #pragma unroll
    for (int i = 0; i < 8; ++i) {
        unsigned short h = rne_bf16(fv[i]);
        hh[i] = (short)h;
        ll[i] = (short)rne_bf16(fv[i] - bf2f(h));
    }
    unsigned short* dst = Wb + (size_t)zi * 131072 + (size_t)row * KS;
    *(short8*)(dst + k0)       = hh;
    *(short8*)(dst + 256 + k0) = ll;
}

// ---------------------------------------------------------------------------
// x|y -> xs: [36864][512] planar (h | l). Done ONCE; proj then async-stages
// A like B (no in-kernel split, no divergence, x fetched from HBM once).
// grid = 4608 x 256 (32 threads per 256-float row).
// ---------------------------------------------------------------------------
__global__ __launch_bounds__(256) void convx_kernel(
    const float* __restrict__ x, const float* __restrict__ y,
    unsigned short* __restrict__ xs)
{
    const int g   = blockIdx.x * 256 + threadIdx.x;  // < 1179648
    const int row = g >> 5;
    const int off = (g & 31) * 8;
    const float* src = (row < ROWS_X) ? (x + (size_t)row * DD)
                                      : (y + (size_t)(row - ROWS_X) * DD);
    float4 v0 = *(const float4*)(src + off);
    float4 v1 = *(const float4*)(src + off + 4);
    const float fv[8] = {v0.x, v0.y, v0.z, v0.w, v1.x, v1.y, v1.z, v1.w};
    short8 hh, ll;
    #pragma unroll
    for (int i = 0; i < 8; ++i) {
        unsigned short h = rne_bf16(fv[i]);
        hh[i] = (short)h;
        ll[i] = (short)rne_bf16(fv[i] - bf2f(h));
    }
    unsigned short* dst = xs + (size_t)row * KS;
    *(short8*)(dst + off)       = hh;
    *(short8*)(dst + 256 + off) = ll;
}

// ---------------------------------------------------------------------------
// Projections via MFMA (k'=768 planar, 12 x 64-slot windows). Both operands
// async-staged XOR-swizzled. z=0 -> Qa, z=1 -> Kb (planar [h|l]);
// z=2 -> Vt[b][d][j] plain bf16.  grid = (288, 2, 3)
// ---------------------------------------------------------------------------
__global__ __launch_bounds__(256) void proj_kernel(
    const unsigned short* __restrict__ xs,
    const unsigned short* __restrict__ Wb,
    unsigned short* __restrict__ Qa, unsigned short* __restrict__ Kb,
    unsigned short* __restrict__ Vt)
{
    const int z    = blockIdx.z;
    const int row0 = blockIdx.x * 128;
    const int col0 = blockIdx.y * 128;
    const unsigned short* Asrc = xs + (size_t)row0 * KS;
    const unsigned short* Bsrc = Wb + (size_t)z * 131072 + (size_t)col0 * KS;

    __shared__ unsigned short Ab[128][64];
    __shared__ unsigned short Bb[128][64];

    const int t = threadIdx.x;
    const int wave = t >> 6, lane = t & 63, quad = lane >> 4, lid = lane & 15;
    const int wrow = (wave & 1) * 64, wcol = (wave >> 1) * 64;

    f32x4 acc[4][4];
    #pragma unroll
    for (int i = 0; i < 4; ++i)
        #pragma unroll
        for (int j = 0; j < 4; ++j) acc[i][j] = (f32x4){0.f, 0.f, 0.f, 0.f};

    for (int w = 0; w < 12; ++w) {
        stage64(&Ab[0][0], Asrc, awin(w), wave, lane);
        stage64(&Bb[0][0], Bsrc, bwin(w), wave, lane);
        __syncthreads();
        #pragma unroll
        for (int kk = 0; kk < 64; kk += 32) {
            const int c0 = (kk >> 3) + quad;
            short8 af[4], bf_[4];
            frag4_x64(Ab, wrow, lid, c0, af);
            frag4_x64(Bb, wcol, lid, c0, bf_);
            mfma_4x4(af, bf_, acc);
        }
        __syncthreads();
    }

    if (z == 2) {
        #pragma unroll
        for (int i = 0; i < 4; ++i) {
            const int rg = row0 + wrow + i * 16 + quad * 4;
            const int b  = rg >> 9;
            const int j  = rg & 511;
            #pragma unroll
            for (int jt = 0; jt < 4; ++jt) {
                const int col = col0 + wcol + jt * 16 + lid;
                *(ushort4*)(Vt + (size_t)b * DD * MM + (size_t)col * MM + j) =
                    make_ushort4(rne_bf16(acc[i][jt][0]), rne_bf16(acc[i][jt][1]),
                                 rne_bf16(acc[i][jt][2]), rne_bf16(acc[i][jt][3]));
            }
        }
    } else {
        unsigned short* dst = (z == 0) ? Qa : Kb;
        #pragma unroll
        for (int i = 0; i < 4; ++i) {
            const int rg = row0 + wrow + i * 16 + quad * 4;
            #pragma unroll
            for (int r = 0; r < 4; ++r) {
                unsigned short* rowp = dst + (size_t)(rg + r) * KS;
                #pragma unroll
                for (int jt = 0; jt < 4; ++jt) {
                    const int col = col0 + wcol + jt * 16 + lid;
                    const float v = acc[i][jt][r];
                    unsigned short h = rne_bf16(v);
                    rowp[col]       = h;                          // h-plane
                    rowp[256 + col] = rne_bf16(v - bf2f(h));      // l-plane
                }
            }
        }
    }
}

// ---------------------------------------------------------------------------
// Self scores (x-self z<64, y-self z>=64) via MFMA k'=768 planar (12 windows,
// XOR staging), mask epilogue + fused per-block softmax partials.
// grid = (4, 4, 72)
// ---------------------------------------------------------------------------
__global__ __launch_bounds__(256) void scores_self_kernel(
    const unsigned short* __restrict__ Qa,
    const unsigned short* __restrict__ Kb,
    const int* __restrict__ mask_x, const int* __restrict__ mask_y,
    float* __restrict__ Sbase, float2* __restrict__ pstats)
{
    const int z    = blockIdx.z;                     // 0..71
    const int row0 = blockIdx.x * 128;
    const int col0 = blockIdx.y * 128;
    const unsigned short* Asrc = Qa + (size_t)(z * MM + row0) * KS;
    const unsigned short* Bsrc = Kb + (size_t)(z * MM + col0) * KS;
    const int* msk = (z < 64) ? (mask_x + z * MM) : (mask_y + (z - 64) * MM);
    float* S = Sbase + (size_t)z * MM * MM;

    __shared__ unsigned short Ab[128][64];
    __shared__ unsigned short Bb[128][64];
    __shared__ float pm2[128][2];
    __shared__ float ps2[128][2];

    const int t = threadIdx.x;
    const int wave = t >> 6, lane = t & 63, quad = lane >> 4, lid = lane & 15;
    const int wrow = (wave & 1) * 64, wcol = (wave >> 1) * 64;

    f32x4 acc[4][4];
    #pragma unroll
    for (int i = 0; i < 4; ++i)
        #pragma unroll
        for (int j = 0; j < 4; ++j) acc[i][j] = (f32x4){0.f, 0.f, 0.f, 0.f};

    for (int w = 0; w < 12; ++w) {
        stage64(&Ab[0][0], Asrc, awin(w), wave, lane);
        stage64(&Bb[0][0], Bsrc, bwin(w), wave, lane);
        __syncthreads();
        #pragma unroll
        for (int kk = 0; kk < 64; kk += 32) {
            const int c0 = (kk >> 3) + quad;
            short8 af[4], bf_[4];
            frag4_x64(Ab, wrow, lid, c0, af);
            frag4_x64(Bb, wcol, lid, c0, bf_);
            mfma_4x4(af, bf_, acc);
        }
        __syncthreads();
    }

    int mcol[4];
    #pragma unroll
    for (int jt = 0; jt < 4; ++jt) mcol[jt] = msk[col0 + wcol + jt * 16 + lid];

    #pragma unroll
    for (int i = 0; i < 4; ++i) {
        const int rl0 = wrow + i * 16 + quad * 4;
        #pragma unroll
        for (int r = 0; r < 4; ++r) {
            const int rlocal = rl0 + r;
            const int rg = row0 + rlocal;
            const bool mr = (msk[rg] != 0);
            float* Srow = S + (size_t)rg * MM;
            float v[4];
            float mt = -3.4e38f;
            #pragma unroll
            for (int jt = 0; jt < 4; ++jt) {
                const int col = col0 + wcol + jt * 16 + lid;
                const bool valid = mr && (mcol[jt] != 0);
                v[jt] = valid ? acc[i][jt][r] : NEG_FILL_F;
                Srow[col] = v[jt];
                mt = fmaxf(mt, v[jt]);
            }
            #pragma unroll
            for (int o = 1; o < 16; o <<= 1) mt = fmaxf(mt, __shfl_xor(mt, o));
            float se = 0.f;
            #pragma unroll
            for (int jt = 0; jt < 4; ++jt) se += __expf(v[jt] - mt);
            #pragma unroll
            for (int o = 1; o < 16; o <<= 1) se += __shfl_xor(se, o);
            if (lid == 0) { pm2[rlocal][wave >> 1] = mt; ps2[rlocal][wave >> 1] = se; }
        }
    }
    __syncthreads();
    if (t < 128) {
        const float m0 = pm2[t][0], m1 = pm2[t][1];
        const float mm = fmaxf(m0, m1);
        const float ss = ps2[t][0] * __expf(m0 - mm) + ps2[t][1] * __expf(m1 - mm);
        pstats[(size_t)(z * 4 + blockIdx.y) * MM + row0 + t] = make_float2(mm, ss);
    }
}

// ---------------------------------------------------------------------------
// Cross scores (xy) in single bf16, K=256 (feeds softmax only). Reads the
// h-plane of Qa/Kb directly. XOR-swizzled 64-wide tiles. grid = (4, 4, 64)
// ---------------------------------------------------------------------------
__global__ __launch_bounds__(256) void scores_xy_kernel(
    const unsigned short* __restrict__ Qa, const unsigned short* __restrict__ Kb,
    const int* __restrict__ mask_x, const int* __restrict__ mask_y,
    float* __restrict__ Sbase, float* __restrict__ Mbase,
    float2* __restrict__ pstats)
{
    const int z = blockIdx.z;                        // 0..63
    const int n = z >> 3, s = z & 7;
    const int bq = s * 8 + n;                        // x batch
    const int bk = s;                                // y batch (rows 32768+)
    const int row0 = blockIdx.x * 128;
    const int col0 = blockIdx.y * 128;
    const unsigned short* Asrc = Qa + (size_t)(bq * MM + row0) * KS;
    const unsigned short* Bsrc = Kb + (size_t)((ROWS_X + bk * MM) + col0) * KS;
    const int* mq = mask_x + bq * MM;
    const int* mk = mask_y + bk * MM;
    float* Sl = Sbase + (size_t)z * MM * MM;
    float* Ml = Mbase + (size_t)z * MM * MM;

    __shared__ unsigned short Ab[128][64];
    __shared__ unsigned short Bb[128][64];
    __shared__ float pm2[128][2];
    __shared__ float ps2[128][2];

    const int t = threadIdx.x;
    const int wave = t >> 6, lane = t & 63, quad = lane >> 4, lid = lane & 15;
    const int wrow = (wave & 1) * 64, wcol = (wave >> 1) * 64;

    f32x4 acc[4][4];
    #pragma unroll
    for (int i = 0; i < 4; ++i)
        #pragma unroll
        for (int j = 0; j < 4; ++j) acc[i][j] = (f32x4){0.f, 0.f, 0.f, 0.f};

    for (int ck = 0; ck < 4; ++ck) {
        stage64(&Ab[0][0], Asrc, ck * 64, wave, lane);
        stage64(&Bb[0][0], Bsrc, ck * 64, wave, lane);
        __syncthreads();
        #pragma unroll
        for (int kk = 0; kk < 64; kk += 32) {
            const int c0 = (kk >> 3) + quad;
            short8 af[4], bf_[4];
            frag4_x64(Ab, wrow, lid, c0, af);
            frag4_x64(Bb, wcol, lid, c0, bf_);
            mfma_4x4(af, bf_, acc);
        }
        __syncthreads();
    }

    int mcol[4];
    #pragma unroll
    for (int jt = 0; jt < 4; ++jt) mcol[jt] = mk[col0 + wcol + jt * 16 + lid];

    #pragma unroll
    for (int i = 0; i < 4; ++i) {
        const int rl0 = wrow + i * 16 + quad * 4;
        #pragma unroll
        for (int r = 0; r < 4; ++r) {
            const int rlocal = rl0 + r;
            const int rg = row0 + rlocal;
            const bool mr = (mq[rg] != 0);
            float* Srow = Sl + (size_t)rg * MM;
            float* Mrow = Ml + (size_t)rg * MM;
            float v[4];
            float mt = -3.4e38f;
            #pragma unroll
            for (int jt = 0; jt < 4; ++jt) {
                const int col = col0 + wcol + jt * 16 + lid;
                const bool valid = mr && (mcol[jt] != 0);
                v[jt] = valid ? acc[i][jt][r] : NEG_FILL_F;
                Srow[col] = v[jt];
                Mrow[col] = valid ? 1.0f : 0.0f;
                mt = fmaxf(mt, v[jt]);
            }
            #pragma unroll
            for (int o = 1; o < 16; o <<= 1) mt = fmaxf(mt, __shfl_xor(mt, o));
            float se = 0.f;
            #pragma unroll
            for (int jt = 0; jt < 4; ++jt) se += __expf(v[jt] - mt);
            #pragma unroll
            for (int o = 1; o < 16; o <<= 1) se += __shfl_xor(se, o);
            if (lid == 0) { pm2[rlocal][wave >> 1] = mt; ps2[rlocal][wave >> 1] = se; }
        }
    }
    __syncthreads();
    if (t < 128) {
        const float m0 = pm2[t][0], m1 = pm2[t][1];
        const float mm = fmaxf(m0, m1);
        const float ss = ps2[t][0] * __expf(m0 - mm) + ps2[t][1] * __expf(m1 - mm);
        pstats[(size_t)(z * 4 + blockIdx.y) * MM + row0 + t] = make_float2(mm, ss);
    }
}

// ---------------------------------------------------------------------------
// Merge 4 col-block partials per row -> (max, 1/sum). grid = 69632/256 = 272.
// ---------------------------------------------------------------------------
__global__ __launch_bounds__(256) void reduce4_kernel(
    const float2* __restrict__ p, float2* __restrict__ st)
{
    const int row = blockIdx.x * 256 + threadIdx.x;
    const int z = row >> 9, rl = row & 511;
    float m = -3.4e38f, s = 0.f;
    #pragma unroll
    for (int by = 0; by < 4; ++by) {
        float2 v = p[(size_t)(z * 4 + by) * MM + rl];
        float nm = fmaxf(m, v.x);
        s = s * __expf(m - nm) + v.y * __expf(v.x - nm);
        m = nm;
    }
    st[row] = make_float2(m, 1.0f / s);
}

// ---------------------------------------------------------------------------
// Context via MFMA (plain bf16, K'=512). A = exp(S-m) manual-staged into an
// XOR-swizzled [128][64] tile; B = Vt async-copied XOR-swizzled.
// grid = (4, 2, 72)
// ---------------------------------------------------------------------------
__global__ __launch_bounds__(256) void ctx_kernel(
    const float* __restrict__ Sbase, const float2* __restrict__ stats,
    const unsigned short* __restrict__ Vt_base, float* __restrict__ Obase)
{
    const int b = blockIdx.z;
    const float*          S  = Sbase + (size_t)b * MM * MM;
    const float2*         st = stats + (size_t)b * MM;
    const unsigned short* Vt = Vt_base + (size_t)b * DD * MM;
    float*                O  = Obase + (size_t)b * MM * DD;

    const int row0 = blockIdx.x * 128;
    const int col0 = blockIdx.y * 128;

    __shared__ unsigned short Ab[128][64];
    __shared__ unsigned short Bb[128][64];

    const int t = threadIdx.x;
    const int wave = t >> 6, lane = t & 63, quad = lane >> 4, lid = lane & 15;
    const int wrow = (wave & 1) * 64, wcol = (wave >> 1) * 64;

    f32x4 acc[4][4];
    #pragma unroll
    for (int i = 0; i < 4; ++i)
        #pragma unroll
        for (int j = 0; j < 4; ++j) acc[i][j] = (f32x4){0.f, 0.f, 0.f, 0.f};

    for (int ck = 0; ck < 8; ++ck) {
        // B: Vt rows are d (output cols); XOR-swizzled source chunks
        #pragma unroll
        for (int s4 = 0; s4 < 4; ++s4) {
            const int c   = s4 * 256 + wave * 64 + lane;  // 0..1023
            const int r   = c >> 3;
            const int cin = (c & 7) ^ (r & 7);
            gld16(Vt + (size_t)(col0 + r) * MM + ck * 64 + cin * 8,
                  &Bb[0][0] + (size_t)(s4 * 256 + wave * 64) * 8);
        }
        // A: exp(S - m) -> bf16, manual, XOR-swizzled LDS slot
        #pragma unroll
        for (int s4 = 0; s4 < 4; ++s4) {
            const int c    = s4 * 256 + t;     // 0..1023
            const int row  = c >> 3;
            const int j8   = (c & 7) * 8;      // source col group (unswizzled)
            const int slot = (c & 7) ^ (row & 7);
            const float* sp = S + (size_t)(row0 + row) * MM + ck * 64 + j8;
            float4 v0 = *(const float4*)sp;
            float4 v1 = *(const float4*)(sp + 4);
            const float pm = st[row0 + row].x;
            short8 pk;
            pk[0] = (short)rne_bf16(__expf(v0.x - pm));
            pk[1] = (short)rne_bf16(__expf(v0.y - pm));
            pk[2] = (short)rne_bf16(__expf(v0.z - pm));
            pk[3] = (short)rne_bf16(__expf(v0.w - pm));
            pk[4] = (short)rne_bf16(__expf(v1.x - pm));
            pk[5] = (short)rne_bf16(__expf(v1.y - pm));
            pk[6] = (short)rne_bf16(__expf(v1.z - pm));
            pk[7] = (short)rne_bf16(__expf(v1.w - pm));
            *(short8*)&Ab[row][slot * 8] = pk;
        }
        __syncthreads();
        #pragma unroll
        for (int kk = 0; kk < 64; kk += 32) {
            const int c0 = (kk >> 3) + quad;
            short8 af[4], bf_[4];
            frag4_x64(Ab, wrow, lid, c0, af);
            frag4_x64(Bb, wcol, lid, c0, bf_);
            mfma_4x4(af, bf_, acc);
        }
        __syncthreads();
    }

    #pragma unroll
    for (int i = 0; i < 4; ++i) {
        const int rgb = row0 + wrow + i * 16 + quad * 4;
        float inv[4];
        #pragma unroll
        for (int r = 0; r < 4; ++r) inv[r] = st[rgb + r].y;
        #pragma unroll
        for (int jt = 0; jt < 4; ++jt) {
            const int col = col0 + wcol + jt * 16 + lid;
            #pragma unroll
            for (int r = 0; r < 4; ++r)
                O[(size_t)(rgb + r) * DD + col] = acc[i][jt][r] * inv[r];
        }
    }
}

// ---------------------------------------------------------------------------
// In-place softmax transform of the scores_xy slot -> probs_xy.
// ---------------------------------------------------------------------------
__global__ __launch_bounds__(128) void softmax_apply(
    float* __restrict__ S, const float2* __restrict__ stats)
{
    const int row = blockIdx.x;
    const float2 st = stats[row];
    float4* r = (float4*)(S + (size_t)row * MM) + threadIdx.x;
    float4 v = *r;
    v.x = __expf(v.x - st.x) * st.y;
    v.y = __expf(v.y - st.x) * st.y;
    v.z = __expf(v.z - st.x) * st.y;
    v.w = __expf(v.w - st.x) * st.y;
    *r = v;
}

// ---------------------------------------------------------------------------
// y_len: one block per s, 64-lane reduce of mask_y[s,:]; lane n<8 writes n*8+s.
// ---------------------------------------------------------------------------
__global__ void ylen_kernel(const int* __restrict__ mask_y, float* __restrict__ out)
{
    const int s = blockIdx.x;
    const int lane = threadIdx.x;
    int c = 0;
    #pragma unroll
    for (int k = 0; k < 8; ++k) c += (mask_y[s * MM + k * 64 + lane] != 0);
    #pragma unroll
    for (int off = 32; off; off >>= 1) c += __shfl_xor(c, off);
    if (lane < 8) out[lane * 8 + s] = (float)c;
}

// ---------------------------------------------------------------------------
extern "C" void kernel_launch(void* const* d_in, const int* in_sizes, int n_in,
                              void* d_out, int out_size, void* d_ws, size_t ws_size,
                              hipStream_t stream)
{
    const float* x      = (const float*)d_in[0];
    const float* y      = (const float*)d_in[1];
    const int*   mask_x = (const int*)d_in[2];
    const int*   mask_y = (const int*)d_in[3];
    const float* Wq     = (const float*)d_in[4];
    const float* Wk     = (const float*)d_in[5];
    const float* Wv     = (const float*)d_in[6];
    float* out = (float*)d_out;

    // Workspace (~136 MB): Wb | xs | Qa | Kb | Vt | stats | pstats
    unsigned short* Wb = (unsigned short*)d_ws;            // 3*256*512   = 393216
    unsigned short* xs = Wb + 393216;                      // 36864*512   = 18874368
    unsigned short* Qa = xs + 18874368;
    unsigned short* Kb = Qa + 18874368;
    unsigned short* Vt = Kb + 18874368;                    // 72*256*512  = 9437184
    float2* stats_x  = (float2*)(Vt + 9437184);            // 69632 rows contiguous
    float2* stats_xy = stats_x + ROWS_ALL;
    float2* ps_x  = stats_x + (ROWS_ALL + ROWS_X);         // 72 z then 64 z
    float2* ps_xy = ps_x + (64 + 8) * 4 * 512;

    // Output slots (floats, concatenated in reference return order)
    float* out_ctx_x = out;                 // 64*512*256   = 8388608 (+ctx_y)
    float* out_sx    = out + 9437184;       // 64*512*512   = 16777216 (+sy)
    float* out_pxy   = out + 28311552;      // 8*8*512*512  = 16777216
    float* out_mxy   = out + 45088768;      // 8*8*512*512  = 16777216
    float* out_ylen  = out + 61865984;      // 8*8          = 64

    // 1. W -> planar split; x|y -> planar split (once); y_len
    convw_kernel<<<96, 256, 0, stream>>>(Wq, Wk, Wv, Wb);
    convx_kernel<<<4608, 256, 0, stream>>>(x, y, xs);
    ylen_kernel<<<8, 64, 0, stream>>>(mask_y, out_ylen);

    // 2. Projections (MFMA): Qa/Kb planar [h|l], Vt transposed bf16
    proj_kernel<<<dim3(288, 2, 3), 256, 0, stream>>>(xs, Wb, Qa, Kb, Vt);

    // 3. Scores: self (x+y merged, triple-split) and xy (h-plane bf16, K=256)
    scores_self_kernel<<<dim3(4, 4, 72), 256, 0, stream>>>(
        Qa, Kb, mask_x, mask_y, out_sx, ps_x);
    scores_xy_kernel<<<dim3(4, 4, 64), 256, 0, stream>>>(
        Qa, Kb, mask_x, mask_y, out_pxy, out_mxy, ps_xy);

    // 4. Merge partials -> (max, 1/sum) for all 69632 rows
    reduce4_kernel<<<(ROWS_ALL + ROWS_X) / 256, 256, 0, stream>>>(ps_x, stats_x);

    // 5. scores_xy -> probs_xy in place (pxy still LLC-warm)
    softmax_apply<<<ROWS_X, 128, 0, stream>>>(out_pxy, stats_xy);

    // 6. Context GEMMs (x+y merged; exp fused on A-stage)
    ctx_kernel<<<dim3(4, 2, 72), 256, 0, stream>>>(out_sx, stats_x, Vt, out_ctx_x);
}

// Round 4
// 485.160 us; speedup vs baseline: 1.1699x; 1.0652x over previous
//
#include <hip/hip_runtime.h>
#include <cstdint>

// Problem constants (B, BS, M, D) = (64, 8, 512, 256), neg = B/BS = 8
#define NEG_FILL_F (-10000000000.0f)
constexpr int BB     = 64;
constexpr int BS_    = 8;
constexpr int MM     = 512;
constexpr int DD     = 256;
constexpr int ROWS_X = BB * MM;           // 32768
constexpr int ROWS_Y = BS_ * MM;          // 4096
constexpr int ROWS_ALL = ROWS_X + ROWS_Y; // 36864
// Triple-split k' = 768 slots, planar pairing:
//   slots [0,256):   A=h, B=h
//   slots [256,512): A=l, B=h
//   slots [512,768): A=h, B=l
// Storage is 512 shorts/row: [h-plane | l-plane]; h-plane is read twice.
// K-loops run 32-slot windows; window w (0..23) lives in exactly one plane.
constexpr int KS     = 512;               // stored row length (shorts)

typedef __attribute__((ext_vector_type(8))) short short8;   // 8 bf16 = 4 VGPRs
typedef __attribute__((ext_vector_type(4))) float f32x4;    // MFMA C/D

__device__ inline unsigned short rne_bf16(float f) {
    unsigned int u = __float_as_uint(f);
    u = (u + 0x7FFFu + ((u >> 16) & 1u)) >> 16;
    return (unsigned short)u;
}
__device__ inline float bf2f(unsigned short h) {
    return __uint_as_float(((unsigned int)h) << 16);
}

__device__ inline f32x4 mfma16(short8 a, short8 b, f32x4 c) {
    return __builtin_amdgcn_mfma_f32_16x16x32_bf16(a, b, c, 0, 0, 0);
}

// Async global->LDS 16B copy. LDS dst is wave-uniform base; HW adds lane*16.
__device__ inline void gld16(const unsigned short* g, unsigned short* l) {
    __builtin_amdgcn_global_load_lds(
        (const __attribute__((address_space(1))) unsigned int*)g,
        (__attribute__((address_space(3))) unsigned int*)l, 16, 0, 0);
}

__device__ inline void mfma_4x4(const short8 af[4], const short8 bf_[4],
                                f32x4 acc[4][4]) {
    #pragma unroll
    for (int i = 0; i < 4; ++i)
        #pragma unroll
        for (int j = 0; j < 4; ++j)
            acc[i][j] = mfma16(af[i], bf_[j], acc[i][j]);
}

// Window -> column base within the planar [h|l] row (shorts), 32-slot windows.
// A pairing (h,l,h): plane 1 is the l-plane. B pairing (h,h,l): plane 2 is l.
__device__ inline int awin32(int w) { return (((w >> 3) == 1) ? 256 : 0) + (w & 7) * 32; }
__device__ inline int bwin32(int w) { return (((w >> 3) == 2) ? 256 : 0) + (w & 7) * 32; }

// Stage one [128][32] bf16 tile (8 KB), XOR-swizzled (chunk ^= row&3), async.
// LDS chunk c=(r,q) holds global chunk q^(r&3); involution on the read side.
__device__ inline void stage32(unsigned short* dstbase,
                               const unsigned short* __restrict__ src,
                               int srccol, int wave, int lane)
{
    #pragma unroll
    for (int s4 = 0; s4 < 2; ++s4) {
        const int c   = s4 * 256 + wave * 64 + lane;  // 0..511
        const int r   = c >> 2;
        const int cin = (c & 3) ^ (r & 3);
        gld16(src + (size_t)r * KS + srccol + cin * 8,
              dstbase + (size_t)(s4 * 256 + wave * 64) * 8);
    }
}

// 4 fragments, rows rbase+{0,16,32,48}+lid, global chunk = quad, from a
// [*][32] XOR tile (works for 128- or 256-row tiles).
__device__ inline void frag4_x32(const unsigned short (*T)[32], int rbase,
                                 int lid, int quad, short8 f[4])
{
    const int q = quad ^ (lid & 3);
    #pragma unroll
    for (int i = 0; i < 4; ++i)
        f[i] = *(const short8*)&T[rbase + i * 16 + lid][q * 8];
}

// ---------------------------------------------------------------------------
// W -> Wb: [3][256][512] planar (h-plane | l-plane). 96 blocks x 256.
// ---------------------------------------------------------------------------
__global__ __launch_bounds__(256) void convw_kernel(
    const float* __restrict__ Wq, const float* __restrict__ Wk,
    const float* __restrict__ Wv, unsigned short* __restrict__ Wb)
{
    const int g  = blockIdx.x * 256 + threadIdx.x;   // < 24576
    const int e  = g * 8;                            // over 3*65536
    const int zi = e >> 16;
    const int off = e & 65535;
    const int row = off >> 8, k0 = off & 255;
    const float* W = (zi == 0) ? Wq : (zi == 1 ? Wk : Wv);
    float4 v0 = *(const float4*)(W + off);
    float4 v1 = *(const float4*)(W + off + 4);
    const float fv[8] = {v0.x, v0.y, v0.z, v0.w, v1.x, v1.y, v1.z, v1.w};
    short8 hh, ll;
    #pragma unroll
    for (int i = 0; i < 8; ++i) {
        unsigned short h = rne_bf16(fv[i]);
        hh[i] = (short)h;
        ll[i] = (short)rne_bf16(fv[i] - bf2f(h));
    }
    unsigned short* dst = Wb + (size_t)zi * 131072 + (size_t)row * KS;
    *(short8*)(dst + k0)       = hh;
    *(short8*)(dst + 256 + k0) = ll;
}

// ---------------------------------------------------------------------------
// x|y -> xs: [36864][512] planar (h | l). grid = 4608 x 256.
// ---------------------------------------------------------------------------
__global__ __launch_bounds__(256) void convx_kernel(
    const float* __restrict__ x, const float* __restrict__ y,
    unsigned short* __restrict__ xs)
{
    const int g   = blockIdx.x * 256 + threadIdx.x;  // < 1179648
    const int row = g >> 5;
    const int off = (g & 31) * 8;
    const float* src = (row < ROWS_X) ? (x + (size_t)row * DD)
                                      : (y + (size_t)(row - ROWS_X) * DD);
    float4 v0 = *(const float4*)(src + off);
    float4 v1 = *(const float4*)(src + off + 4);
    const float fv[8] = {v0.x, v0.y, v0.z, v0.w, v1.x, v1.y, v1.z, v1.w};
    short8 hh, ll;
    #pragma unroll
    for (int i = 0; i < 8; ++i) {
        unsigned short h = rne_bf16(fv[i]);
        hh[i] = (short)h;
        ll[i] = (short)rne_bf16(fv[i] - bf2f(h));
    }
    unsigned short* dst = xs + (size_t)row * KS;
    *(short8*)(dst + off)       = hh;
    *(short8*)(dst + 256 + off) = ll;
}

// ---------------------------------------------------------------------------
// Projections via MFMA (k'=768 planar, 24 x 32-slot windows, double-buffered
// 2-phase prefetch). XCD-chunked 1D grid: 6 consumers of each A-panel (2 col
// x 3 z) run consecutively on one XCD -> A panel stays in that XCD's L2.
// z=0 -> Qa, z=1 -> Kb (planar [h|l]); z=2 -> Vt[b][d][j]. grid = 1728.
// ---------------------------------------------------------------------------
__global__ __launch_bounds__(256) void proj_kernel(
    const unsigned short* __restrict__ xs,
    const unsigned short* __restrict__ Wb,
    unsigned short* __restrict__ Qa, unsigned short* __restrict__ Kb,
    unsigned short* __restrict__ Vt)
{
    // 1728 = 8 XCD * 216; per XCD: 36 consecutive bx, each with 6 (by,bz)
    const int xcd = blockIdx.x & 7, idx = blockIdx.x >> 3;
    const int lin = xcd * 216 + idx;
    const int bx  = lin / 6;
    const int rem = lin - bx * 6;
    const int z    = rem >> 1;
    const int row0 = bx * 128;
    const int col0 = (rem & 1) * 128;
    const unsigned short* Asrc = xs + (size_t)row0 * KS;
    const unsigned short* Bsrc = Wb + (size_t)z * 131072 + (size_t)col0 * KS;

    __shared__ unsigned short Ab[2][128][32];
    __shared__ unsigned short Bb[2][128][32];

    const int t = threadIdx.x;
    const int wave = t >> 6, lane = t & 63, quad = lane >> 4, lid = lane & 15;
    const int wrow = (wave & 1) * 64, wcol = (wave >> 1) * 64;

    f32x4 acc[4][4];
    #pragma unroll
    for (int i = 0; i < 4; ++i)
        #pragma unroll
        for (int j = 0; j < 4; ++j) acc[i][j] = (f32x4){0.f, 0.f, 0.f, 0.f};

    stage32(&Ab[0][0][0], Asrc, awin32(0), wave, lane);
    stage32(&Bb[0][0][0], Bsrc, bwin32(0), wave, lane);
    __syncthreads();
    int cur = 0;
    for (int w = 0; w < 23; ++w) {
        stage32(&Ab[cur ^ 1][0][0], Asrc, awin32(w + 1), wave, lane);
        stage32(&Bb[cur ^ 1][0][0], Bsrc, bwin32(w + 1), wave, lane);
        short8 af[4], bf_[4];
        frag4_x32(Ab[cur], wrow, lid, quad, af);
        frag4_x32(Bb[cur], wcol, lid, quad, bf_);
        mfma_4x4(af, bf_, acc);
        __syncthreads();
        cur ^= 1;
    }
    {
        short8 af[4], bf_[4];
        frag4_x32(Ab[cur], wrow, lid, quad, af);
        frag4_x32(Bb[cur], wcol, lid, quad, bf_);
        mfma_4x4(af, bf_, acc);
    }

    if (z == 2) {
        #pragma unroll
        for (int i = 0; i < 4; ++i) {
            const int rg = row0 + wrow + i * 16 + quad * 4;
            const int b  = rg >> 9;
            const int j  = rg & 511;
            #pragma unroll
            for (int jt = 0; jt < 4; ++jt) {
                const int col = col0 + wcol + jt * 16 + lid;
                *(ushort4*)(Vt + (size_t)b * DD * MM + (size_t)col * MM + j) =
                    make_ushort4(rne_bf16(acc[i][jt][0]), rne_bf16(acc[i][jt][1]),
                                 rne_bf16(acc[i][jt][2]), rne_bf16(acc[i][jt][3]));
            }
        }
    } else {
        unsigned short* dst = (z == 0) ? Qa : Kb;
        #pragma unroll
        for (int i = 0; i < 4; ++i) {
            const int rg = row0 + wrow + i * 16 + quad * 4;
            #pragma unroll
            for (int r = 0; r < 4; ++r) {
                unsigned short* rowp = dst + (size_t)(rg + r) * KS;
                #pragma unroll
                for (int jt = 0; jt < 4; ++jt) {
                    const int col = col0 + wcol + jt * 16 + lid;
                    const float v = acc[i][jt][r];
                    unsigned short h = rne_bf16(v);
                    rowp[col]       = h;                          // h-plane
                    rowp[256 + col] = rne_bf16(v - bf2f(h));      // l-plane
                }
            }
        }
    }
}

// ---------------------------------------------------------------------------
// Self scores (x-self z<64, y-self z>=64), k'=768 planar, 24 windows,
// double-buffered prefetch, XCD-chunked (16 blocks of one z per XCD -> 1 MB
// Q/K panel L2-resident). Mask epilogue + fused softmax partials. grid = 1152.
// ---------------------------------------------------------------------------
__global__ __launch_bounds__(256) void scores_self_kernel(
    const unsigned short* __restrict__ Qa,
    const unsigned short* __restrict__ Kb,
    const int* __restrict__ mask_x, const int* __restrict__ mask_y,
    float* __restrict__ Sbase, float2* __restrict__ pstats)
{
    // 1152 = 8 * 144; per XCD: 9 z, 16 blocks each
    const int xcd = blockIdx.x & 7, idx = blockIdx.x >> 3;
    const int lin = xcd * 144 + idx;
    const int z   = lin >> 4;
    const int rem = lin & 15;
    const int row0 = (rem & 3) * 128;
    const int col0 = (rem >> 2) * 128;
    const int by   = rem >> 2;
    const unsigned short* Asrc = Qa + (size_t)(z * MM + row0) * KS;
    const unsigned short* Bsrc = Kb + (size_t)(z * MM + col0) * KS;
    const int* msk = (z < 64) ? (mask_x + z * MM) : (mask_y + (z - 64) * MM);
    float* S = Sbase + (size_t)z * MM * MM;

    __shared__ unsigned short Ab[2][128][32];
    __shared__ unsigned short Bb[2][128][32];
    __shared__ float pm2[128][2];
    __shared__ float ps2[128][2];

    const int t = threadIdx.x;
    const int wave = t >> 6, lane = t & 63, quad = lane >> 4, lid = lane & 15;
    const int wrow = (wave & 1) * 64, wcol = (wave >> 1) * 64;

    f32x4 acc[4][4];
    #pragma unroll
    for (int i = 0; i < 4; ++i)
        #pragma unroll
        for (int j = 0; j < 4; ++j) acc[i][j] = (f32x4){0.f, 0.f, 0.f, 0.f};

    stage32(&Ab[0][0][0], Asrc, awin32(0), wave, lane);
    stage32(&Bb[0][0][0], Bsrc, bwin32(0), wave, lane);
    __syncthreads();
    int cur = 0;
    for (int w = 0; w < 23; ++w) {
        stage32(&Ab[cur ^ 1][0][0], Asrc, awin32(w + 1), wave, lane);
        stage32(&Bb[cur ^ 1][0][0], Bsrc, bwin32(w + 1), wave, lane);
        short8 af[4], bf_[4];
        frag4_x32(Ab[cur], wrow, lid, quad, af);
        frag4_x32(Bb[cur], wcol, lid, quad, bf_);
        mfma_4x4(af, bf_, acc);
        __syncthreads();
        cur ^= 1;
    }
    {
        short8 af[4], bf_[4];
        frag4_x32(Ab[cur], wrow, lid, quad, af);
        frag4_x32(Bb[cur], wcol, lid, quad, bf_);
        mfma_4x4(af, bf_, acc);
    }

    int mcol[4];
    #pragma unroll
    for (int jt = 0; jt < 4; ++jt) mcol[jt] = msk[col0 + wcol + jt * 16 + lid];

    #pragma unroll
    for (int i = 0; i < 4; ++i) {
        const int rl0 = wrow + i * 16 + quad * 4;
        #pragma unroll
        for (int r = 0; r < 4; ++r) {
            const int rlocal = rl0 + r;
            const int rg = row0 + rlocal;
            const bool mr = (msk[rg] != 0);
            float* Srow = S + (size_t)rg * MM;
            float v[4];
            float mt = -3.4e38f;
            #pragma unroll
            for (int jt = 0; jt < 4; ++jt) {
                const int col = col0 + wcol + jt * 16 + lid;
                const bool valid = mr && (mcol[jt] != 0);
                v[jt] = valid ? acc[i][jt][r] : NEG_FILL_F;
                Srow[col] = v[jt];
                mt = fmaxf(mt, v[jt]);
            }
            #pragma unroll
            for (int o = 1; o < 16; o <<= 1) mt = fmaxf(mt, __shfl_xor(mt, o));
            float se = 0.f;
            #pragma unroll
            for (int jt = 0; jt < 4; ++jt) se += __expf(v[jt] - mt);
            #pragma unroll
            for (int o = 1; o < 16; o <<= 1) se += __shfl_xor(se, o);
            if (lid == 0) { pm2[rlocal][wave >> 1] = mt; ps2[rlocal][wave >> 1] = se; }
        }
    }
    __syncthreads();
    if (t < 128) {
        const float m0 = pm2[t][0], m1 = pm2[t][1];
        const float mm = fmaxf(m0, m1);
        const float ss = ps2[t][0] * __expf(m0 - mm) + ps2[t][1] * __expf(m1 - mm);
        pstats[(size_t)(z * 4 + by) * MM + row0 + t] = make_float2(mm, ss);
    }
}

// ---------------------------------------------------------------------------
// Cross scores (xy), single bf16 K=256 (h-plane), 8 windows, double-buffered.
// XCD-chunked s-major: 8 consecutive blocks share the K(s) panel. grid = 1024.
// ---------------------------------------------------------------------------
__global__ __launch_bounds__(256) void scores_xy_kernel(
    const unsigned short* __restrict__ Qa, const unsigned short* __restrict__ Kb,
    const int* __restrict__ mask_x, const int* __restrict__ mask_y,
    float* __restrict__ Sbase, float* __restrict__ Mbase,
    float2* __restrict__ pstats)
{
    // 1024 = 8 * 128; per XCD: 8 zz (s-major), 16 blocks each
    const int xcd = blockIdx.x & 7, idx = blockIdx.x >> 3;
    const int lin = xcd * 128 + idx;
    const int zz  = lin >> 4;            // s-major order
    const int rem = lin & 15;
    const int s = zz >> 3, n = zz & 7;
    const int zo = n * 8 + s;            // output slot (reference order)
    const int bq = s * 8 + n;            // x batch
    const int bk = s;                    // y batch
    const int row0 = (rem & 3) * 128;
    const int col0 = (rem >> 2) * 128;
    const int by   = rem >> 2;
    const unsigned short* Asrc = Qa + (size_t)(bq * MM + row0) * KS;
    const unsigned short* Bsrc = Kb + (size_t)((ROWS_X + bk * MM) + col0) * KS;
    const int* mq = mask_x + bq * MM;
    const int* mk = mask_y + bk * MM;
    float* Sl = Sbase + (size_t)zo * MM * MM;
    float* Ml = Mbase + (size_t)zo * MM * MM;

    __shared__ unsigned short Ab[2][128][32];
    __shared__ unsigned short Bb[2][128][32];
    __shared__ float pm2[128][2];
    __shared__ float ps2[128][2];

    const int t = threadIdx.x;
    const int wave = t >> 6, lane = t & 63, quad = lane >> 4, lid = lane & 15;
    const int wrow = (wave & 1) * 64, wcol = (wave >> 1) * 64;

    f32x4 acc[4][4];
    #pragma unroll
    for (int i = 0; i < 4; ++i)
        #pragma unroll
        for (int j = 0; j < 4; ++j) acc[i][j] = (f32x4){0.f, 0.f, 0.f, 0.f};

    stage32(&Ab[0][0][0], Asrc, 0, wave, lane);
    stage32(&Bb[0][0][0], Bsrc, 0, wave, lane);
    __syncthreads();
    int cur = 0;
    for (int w = 0; w < 7; ++w) {
        stage32(&Ab[cur ^ 1][0][0], Asrc, (w + 1) * 32, wave, lane);
        stage32(&Bb[cur ^ 1][0][0], Bsrc, (w + 1) * 32, wave, lane);
        short8 af[4], bf_[4];
        frag4_x32(Ab[cur], wrow, lid, quad, af);
        frag4_x32(Bb[cur], wcol, lid, quad, bf_);
        mfma_4x4(af, bf_, acc);
        __syncthreads();
        cur ^= 1;
    }
    {
        short8 af[4], bf_[4];
        frag4_x32(Ab[cur], wrow, lid, quad, af);
        frag4_x32(Bb[cur], wcol, lid, quad, bf_);
        mfma_4x4(af, bf_, acc);
    }

    int mcol[4];
    #pragma unroll
    for (int jt = 0; jt < 4; ++jt) mcol[jt] = mk[col0 + wcol + jt * 16 + lid];

    #pragma unroll
    for (int i = 0; i < 4; ++i) {
        const int rl0 = wrow + i * 16 + quad * 4;
        #pragma unroll
        for (int r = 0; r < 4; ++r) {
            const int rlocal = rl0 + r;
            const int rg = row0 + rlocal;
            const bool mr = (mq[rg] != 0);
            float* Srow = Sl + (size_t)rg * MM;
            float* Mrow = Ml + (size_t)rg * MM;
            float v[4];
            float mt = -3.4e38f;
            #pragma unroll
            for (int jt = 0; jt < 4; ++jt) {
                const int col = col0 + wcol + jt * 16 + lid;
                const bool valid = mr && (mcol[jt] != 0);
                v[jt] = valid ? acc[i][jt][r] : NEG_FILL_F;
                Srow[col] = v[jt];
                Mrow[col] = valid ? 1.0f : 0.0f;
                mt = fmaxf(mt, v[jt]);
            }
            #pragma unroll
            for (int o = 1; o < 16; o <<= 1) mt = fmaxf(mt, __shfl_xor(mt, o));
            float se = 0.f;
            #pragma unroll
            for (int jt = 0; jt < 4; ++jt) se += __expf(v[jt] - mt);
            #pragma unroll
            for (int o = 1; o < 16; o <<= 1) se += __shfl_xor(se, o);
            if (lid == 0) { pm2[rlocal][wave >> 1] = mt; ps2[rlocal][wave >> 1] = se; }
        }
    }
    __syncthreads();
    if (t < 128) {
        const float m0 = pm2[t][0], m1 = pm2[t][1];
        const float mm = fmaxf(m0, m1);
        const float ss = ps2[t][0] * __expf(m0 - mm) + ps2[t][1] * __expf(m1 - mm);
        pstats[(size_t)(zo * 4 + by) * MM + row0 + t] = make_float2(mm, ss);
    }
}

// ---------------------------------------------------------------------------
// Merge 4 col-block partials per SELF row -> (max, 1/sum). grid = 144.
// All-masked rows merge to (NEG_FILL, 1/512) = uniform softmax (jax match).
// ---------------------------------------------------------------------------
__global__ __launch_bounds__(256) void reduce4_kernel(
    const float2* __restrict__ p, float2* __restrict__ st)
{
    const int row = blockIdx.x * 256 + threadIdx.x;
    const int z = row >> 9, rl = row & 511;
    float m = -3.4e38f, s = 0.f;
    #pragma unroll
    for (int by = 0; by < 4; ++by) {
        float2 v = p[(size_t)(z * 4 + by) * MM + rl];
        float nm = fmaxf(m, v.x);
        s = s * __expf(m - nm) + v.y * __expf(v.x - nm);
        m = nm;
    }
    st[row] = make_float2(m, 1.0f / s);
}

// ---------------------------------------------------------------------------
// Context via MFMA (plain bf16, K'=512, 16 windows, double-buffered). 512
// threads, 8 waves (2x4): full 256-col output per block -> S read + exp done
// ONCE (was twice). A = exp(S-m) manual XOR-staged [128][32]; B = Vt async
// [256][32]. XCD-chunked (4 blocks of one batch per chunk). grid = 288.
// ---------------------------------------------------------------------------
__global__ __launch_bounds__(512) void ctx_kernel(
    const float* __restrict__ Sbase, const float2* __restrict__ stats,
    const unsigned short* __restrict__ Vt_base, float* __restrict__ Obase)
{
    // 288 = 8 * 36; per XCD: 9 batches x 4 row-blocks
    const int xcd = blockIdx.x & 7, idx = blockIdx.x >> 3;
    const int lin = xcd * 36 + idx;
    const int b    = lin >> 2;
    const int row0 = (lin & 3) * 128;
    const float*          S  = Sbase + (size_t)b * MM * MM;
    const float2*         st = stats + (size_t)b * MM;
    const unsigned short* Vt = Vt_base + (size_t)b * DD * MM;
    float*                O  = Obase + (size_t)b * MM * DD;

    __shared__ unsigned short Abuf[2][128][32];
    __shared__ unsigned short Bbuf[2][256][32];

    const int t = threadIdx.x;
    const int wave = t >> 6, lane = t & 63, quad = lane >> 4, lid = lane & 15;
    const int wrow = (wave & 1) * 64, wcol = (wave >> 1) * 64;

    f32x4 acc[4][4];
    #pragma unroll
    for (int i = 0; i < 4; ++i)
        #pragma unroll
        for (int j = 0; j < 4; ++j) acc[i][j] = (f32x4){0.f, 0.f, 0.f, 0.f};

    // stagers (w = window index over K'=512, 16 windows)
    auto stageB = [&](unsigned short* dstbase, int w) {
        #pragma unroll
        for (int s4 = 0; s4 < 2; ++s4) {
            const int c   = s4 * 512 + wave * 64 + lane;  // 0..1023
            const int r   = c >> 2;
            const int cin = (c & 3) ^ (r & 3);
            gld16(Vt + (size_t)r * MM + w * 32 + cin * 8,
                  dstbase + (size_t)(s4 * 512 + wave * 64) * 8);
        }
    };
    auto stageA = [&](unsigned short (*Ab)[32], int w) {
        const int c    = t;                // 0..511
        const int r    = c >> 2;
        const int q    = c & 3;
        const int slot = q ^ (r & 3);
        const float* sp = S + (size_t)(row0 + r) * MM + w * 32 + q * 8;
        float4 v0 = *(const float4*)sp;
        float4 v1 = *(const float4*)(sp + 4);
        const float pm = st[row0 + r].x;
        short8 pk;
        pk[0] = (short)rne_bf16(__expf(v0.x - pm));
        pk[1] = (short)rne_bf16(__expf(v0.y - pm));
        pk[2] = (short)rne_bf16(__expf(v0.z - pm));
        pk[3] = (short)rne_bf16(__expf(v0.w - pm));
        pk[4] = (short)rne_bf16(__expf(v1.x - pm));
        pk[5] = (short)rne_bf16(__expf(v1.y - pm));
        pk[6] = (short)rne_bf16(__expf(v1.z - pm));
        pk[7] = (short)rne_bf16(__expf(v1.w - pm));
        *(short8*)&Ab[r][slot * 8] = pk;
    };

    stageB(&Bbuf[0][0][0], 0);
    stageA(Abuf[0], 0);
    __syncthreads();
    int cur = 0;
    for (int w = 0; w < 15; ++w) {
        stageB(&Bbuf[cur ^ 1][0][0], w + 1);
        stageA(Abuf[cur ^ 1], w + 1);
        short8 af[4], bf_[4];
        frag4_x32(Abuf[cur], wrow, lid, quad, af);
        frag4_x32(Bbuf[cur], wcol, lid, quad, bf_);
        mfma_4x4(af, bf_, acc);
        __syncthreads();
        cur ^= 1;
    }
    {
        short8 af[4], bf_[4];
        frag4_x32(Abuf[cur], wrow, lid, quad, af);
        frag4_x32(Bbuf[cur], wcol, lid, quad, bf_);
        mfma_4x4(af, bf_, acc);
    }

    #pragma unroll
    for (int i = 0; i < 4; ++i) {
        const int rgb = row0 + wrow + i * 16 + quad * 4;
        float inv[4];
        #pragma unroll
        for (int r = 0; r < 4; ++r) inv[r] = st[rgb + r].y;
        #pragma unroll
        for (int jt = 0; jt < 4; ++jt) {
            const int col = wcol + jt * 16 + lid;
            #pragma unroll
            for (int r = 0; r < 4; ++r)
                O[(size_t)(rgb + r) * DD + col] = acc[i][jt][r] * inv[r];
        }
    }
}

// ---------------------------------------------------------------------------
// In-place softmax of scores_xy -> probs_xy, merging its own 4 partials per
// row (reduce4 no longer covers xy). One block per row, 128 threads.
// ---------------------------------------------------------------------------
__global__ __launch_bounds__(128) void softmax_apply(
    float* __restrict__ S, const float2* __restrict__ ps)
{
    const int row = blockIdx.x;
    const int z = row >> 9, rl = row & 511;
    float m = -3.4e38f, s = 0.f;
    #pragma unroll
    for (int by = 0; by < 4; ++by) {
        float2 v = ps[(size_t)(z * 4 + by) * MM + rl];
        float nm = fmaxf(m, v.x);
        s = s * __expf(m - nm) + v.y * __expf(v.x - nm);
        m = nm;
    }
    const float inv = 1.0f / s;
    float4* r = (float4*)(S + (size_t)row * MM) + threadIdx.x;
    float4 v = *r;
    v.x = __expf(v.x - m) * inv;
    v.y = __expf(v.y - m) * inv;
    v.z = __expf(v.z - m) * inv;
    v.w = __expf(v.w - m) * inv;
    *r = v;
}

// ---------------------------------------------------------------------------
// y_len: one block per s, 64-lane reduce of mask_y[s,:]; lane n<8 writes n*8+s.
// ---------------------------------------------------------------------------
__global__ void ylen_kernel(const int* __restrict__ mask_y, float* __restrict__ out)
{
    const int s = blockIdx.x;
    const int lane = threadIdx.x;
    int c = 0;
    #pragma unroll
    for (int k = 0; k < 8; ++k) c += (mask_y[s * MM + k * 64 + lane] != 0);
    #pragma unroll
    for (int off = 32; off; off >>= 1) c += __shfl_xor(c, off);
    if (lane < 8) out[lane * 8 + s] = (float)c;
}

// ---------------------------------------------------------------------------
extern "C" void kernel_launch(void* const* d_in, const int* in_sizes, int n_in,
                              void* d_out, int out_size, void* d_ws, size_t ws_size,
                              hipStream_t stream)
{
    const float* x      = (const float*)d_in[0];
    const float* y      = (const float*)d_in[1];
    const int*   mask_x = (const int*)d_in[2];
    const int*   mask_y = (const int*)d_in[3];
    const float* Wq     = (const float*)d_in[4];
    const float* Wk     = (const float*)d_in[5];
    const float* Wv     = (const float*)d_in[6];
    float* out = (float*)d_out;

    // Workspace: Wb | xs | Qa | Kb | Vt | stats_x | ps_x | ps_xy
    unsigned short* Wb = (unsigned short*)d_ws;            // 3*256*512   = 393216
    unsigned short* xs = Wb + 393216;                      // 36864*512   = 18874368
    unsigned short* Qa = xs + 18874368;
    unsigned short* Kb = Qa + 18874368;
    unsigned short* Vt = Kb + 18874368;                    // 72*256*512  = 9437184
    float2* stats_x = (float2*)(Vt + 9437184);             // ROWS_ALL
    float2* ps_x    = stats_x + ROWS_ALL;                  // 72*4*512
    float2* ps_xy   = ps_x + 72 * 4 * 512;                 // 64*4*512

    // Output slots (floats, concatenated in reference return order)
    float* out_ctx_x = out;                 // 64*512*256   = 8388608 (+ctx_y)
    float* out_sx    = out + 9437184;       // 64*512*512   = 16777216 (+sy)
    float* out_pxy   = out + 28311552;      // 8*8*512*512  = 16777216
    float* out_mxy   = out + 45088768;      // 8*8*512*512  = 16777216
    float* out_ylen  = out + 61865984;      // 8*8          = 64

    // 1. W -> planar split; x|y -> planar split (once); y_len
    convw_kernel<<<96, 256, 0, stream>>>(Wq, Wk, Wv, Wb);
    convx_kernel<<<4608, 256, 0, stream>>>(x, y, xs);
    ylen_kernel<<<8, 64, 0, stream>>>(mask_y, out_ylen);

    // 2. Projections (MFMA, dbuf prefetch, XCD-chunked)
    proj_kernel<<<1728, 256, 0, stream>>>(xs, Wb, Qa, Kb, Vt);

    // 3. Scores: self (triple-split) and xy (h-plane bf16, K=256)
    scores_self_kernel<<<1152, 256, 0, stream>>>(
        Qa, Kb, mask_x, mask_y, out_sx, ps_x);
    scores_xy_kernel<<<1024, 256, 0, stream>>>(
        Qa, Kb, mask_x, mask_y, out_pxy, out_mxy, ps_xy);

    // 4. Merge self partials -> (max, 1/sum)
    reduce4_kernel<<<ROWS_ALL / 256, 256, 0, stream>>>(ps_x, stats_x);

    // 5. scores_xy -> probs_xy in place (merges its own partials)
    softmax_apply<<<ROWS_X, 128, 0, stream>>>(out_pxy, ps_xy);

    // 6. Context GEMMs (full-width blocks, exp fused once)
    ctx_kernel<<<288, 512, 0, stream>>>(out_sx, stats_x, Vt, out_ctx_x);
}

// Round 6
// 465.073 us; speedup vs baseline: 1.2204x; 1.0432x over previous
//
#include <hip/hip_runtime.h>
#include <cstdint>

// Problem constants (B, BS, M, D) = (64, 8, 512, 256), neg = B/BS = 8
#define NEG_FILL_F (-10000000000.0f)
constexpr int BB     = 64;
constexpr int BS_    = 8;
constexpr int MM     = 512;
constexpr int DD     = 256;
constexpr int ROWS_X = BB * MM;           // 32768
constexpr int ROWS_Y = BS_ * MM;          // 4096
constexpr int ROWS_ALL = ROWS_X + ROWS_Y; // 36864
// Triple-split k' = 768 slots, planar pairing:
//   slots [0,256):   A=h, B=h
//   slots [256,512): A=l, B=h
//   slots [512,768): A=h, B=l
// Storage is 512 shorts/row: [h-plane | l-plane]; h-plane is read twice.
// K-loops run 32-slot windows; window w (0..23) lives in exactly one plane.
constexpr int KS     = 512;               // stored row length (shorts)

typedef __attribute__((ext_vector_type(8))) short short8;   // 8 bf16 = 4 VGPRs
typedef __attribute__((ext_vector_type(4))) float f32x4;    // MFMA C/D

__device__ inline unsigned short rne_bf16(float f) {
    unsigned int u = __float_as_uint(f);
    u = (u + 0x7FFFu + ((u >> 16) & 1u)) >> 16;
    return (unsigned short)u;
}
__device__ inline float bf2f(unsigned short h) {
    return __uint_as_float(((unsigned int)h) << 16);
}

__device__ inline f32x4 mfma16(short8 a, short8 b, f32x4 c) {
    return __builtin_amdgcn_mfma_f32_16x16x32_bf16(a, b, c, 0, 0, 0);
}

// Async global->LDS 16B copy. LDS dst MUST be wave-uniform; HW adds lane*16.
__device__ inline void gld16(const unsigned short* g, unsigned short* l) {
    __builtin_amdgcn_global_load_lds(
        (const __attribute__((address_space(1))) unsigned int*)g,
        (__attribute__((address_space(3))) unsigned int*)l, 16, 0, 0);
}

// Window -> column base within the planar [h|l] row (shorts), 32-slot windows.
// A pairing (h,l,h): plane 1 is the l-plane. B pairing (h,h,l): plane 2 is l.
__device__ inline int awin32(int w) { return (((w >> 3) == 1) ? 256 : 0) + (w & 7) * 32; }
__device__ inline int bwin32(int w) { return (((w >> 3) == 2) ? 256 : 0) + (w & 7) * 32; }

// Stage one [128][32] bf16 tile (8 KB), XOR-swizzled (chunk ^= row&3), async.
// (256-thread version used by proj.) LDS dst wave-uniform, src per-lane.
__device__ inline void stage32(unsigned short* dstbase,
                               const unsigned short* __restrict__ src,
                               int srccol, int wave, int lane)
{
    #pragma unroll
    for (int s4 = 0; s4 < 2; ++s4) {
        const int c   = s4 * 256 + wave * 64 + lane;  // 0..511
        const int r   = c >> 2;
        const int cin = (c & 3) ^ (r & 3);
        gld16(src + (size_t)r * KS + srccol + cin * 8,
              dstbase + (size_t)(s4 * 256 + wave * 64) * 8);
    }
}

// 4 fragments, rows rbase+{0,16,32,48}+lid, global chunk = quad, from a
// [*][32] XOR tile (any row count).
__device__ inline void frag4_x32(const unsigned short (*T)[32], int rbase,
                                 int lid, int quad, short8 f[4])
{
    const int q = quad ^ (lid & 3);
    #pragma unroll
    for (int i = 0; i < 4; ++i)
        f[i] = *(const short8*)&T[rbase + i * 16 + lid][q * 8];
}

// ---------------------------------------------------------------------------
// W -> Wb: [3][256][512] planar (h-plane | l-plane). 96 blocks x 256.
// ---------------------------------------------------------------------------
__global__ __launch_bounds__(256) void convw_kernel(
    const float* __restrict__ Wq, const float* __restrict__ Wk,
    const float* __restrict__ Wv, unsigned short* __restrict__ Wb)
{
    const int g  = blockIdx.x * 256 + threadIdx.x;   // < 24576
    const int e  = g * 8;                            // over 3*65536
    const int zi = e >> 16;
    const int off = e & 65535;
    const int row = off >> 8, k0 = off & 255;
    const float* W = (zi == 0) ? Wq : (zi == 1 ? Wk : Wv);
    float4 v0 = *(const float4*)(W + off);
    float4 v1 = *(const float4*)(W + off + 4);
    const float fv[8] = {v0.x, v0.y, v0.z, v0.w, v1.x, v1.y, v1.z, v1.w};
    short8 hh, ll;
    #pragma unroll
    for (int i = 0; i < 8; ++i) {
        unsigned short h = rne_bf16(fv[i]);
        hh[i] = (short)h;
        ll[i] = (short)rne_bf16(fv[i] - bf2f(h));
    }
    unsigned short* dst = Wb + (size_t)zi * 131072 + (size_t)row * KS;
    *(short8*)(dst + k0)       = hh;
    *(short8*)(dst + 256 + k0) = ll;
}

// ---------------------------------------------------------------------------
// x|y -> xs: [36864][512] planar (h | l). grid = 4608 x 256.
// ---------------------------------------------------------------------------
__global__ __launch_bounds__(256) void convx_kernel(
    const float* __restrict__ x, const float* __restrict__ y,
    unsigned short* __restrict__ xs)
{
    const int g   = blockIdx.x * 256 + threadIdx.x;  // < 1179648
    const int row = g >> 5;
    const int off = (g & 31) * 8;
    const float* src = (row < ROWS_X) ? (x + (size_t)row * DD)
                                      : (y + (size_t)(row - ROWS_X) * DD);
    float4 v0 = *(const float4*)(src + off);
    float4 v1 = *(const float4*)(src + off + 4);
    const float fv[8] = {v0.x, v0.y, v0.z, v0.w, v1.x, v1.y, v1.z, v1.w};
    short8 hh, ll;
    #pragma unroll
    for (int i = 0; i < 8; ++i) {
        unsigned short h = rne_bf16(fv[i]);
        hh[i] = (short)h;
        ll[i] = (short)rne_bf16(fv[i] - bf2f(h));
    }
    unsigned short* dst = xs + (size_t)row * KS;
    *(short8*)(dst + off)       = hh;
    *(short8*)(dst + 256 + off) = ll;
}

// ---------------------------------------------------------------------------
// Projections via MFMA (k'=768 planar, 24 x 32-slot windows, double-buffered
// 2-phase prefetch). XCD-chunked: 6 consumers of each A-panel on one XCD.
// z=0 -> Qa, z=1 -> Kb (planar [h|l]); z=2 -> Vt[b][d][j]. grid = 1728.
// ---------------------------------------------------------------------------
__global__ __launch_bounds__(256) void proj_kernel(
    const unsigned short* __restrict__ xs,
    const unsigned short* __restrict__ Wb,
    unsigned short* __restrict__ Qa, unsigned short* __restrict__ Kb,
    unsigned short* __restrict__ Vt)
{
    // 1728 = 8 XCD * 216; per XCD: 36 consecutive bx, each with 6 (by,bz)
    const int xcd = blockIdx.x & 7, idx = blockIdx.x >> 3;
    const int lin = xcd * 216 + idx;
    const int bx  = lin / 6;
    const int rem = lin - bx * 6;
    const int z    = rem >> 1;
    const int row0 = bx * 128;
    const int col0 = (rem & 1) * 128;
    const unsigned short* Asrc = xs + (size_t)row0 * KS;
    const unsigned short* Bsrc = Wb + (size_t)z * 131072 + (size_t)col0 * KS;

    __shared__ unsigned short Ab[2][128][32];
    __shared__ unsigned short Bb[2][128][32];

    const int t = threadIdx.x;
    const int wave = t >> 6, lane = t & 63, quad = lane >> 4, lid = lane & 15;
    const int wrow = (wave & 1) * 64, wcol = (wave >> 1) * 64;

    f32x4 acc[4][4];
    #pragma unroll
    for (int i = 0; i < 4; ++i)
        #pragma unroll
        for (int j = 0; j < 4; ++j) acc[i][j] = (f32x4){0.f, 0.f, 0.f, 0.f};

    stage32(&Ab[0][0][0], Asrc, awin32(0), wave, lane);
    stage32(&Bb[0][0][0], Bsrc, bwin32(0), wave, lane);
    __syncthreads();
    int cur = 0;
    for (int w = 0; w < 23; ++w) {
        stage32(&Ab[cur ^ 1][0][0], Asrc, awin32(w + 1), wave, lane);
        stage32(&Bb[cur ^ 1][0][0], Bsrc, bwin32(w + 1), wave, lane);
        short8 af[4], bf_[4];
        frag4_x32(Ab[cur], wrow, lid, quad, af);
        frag4_x32(Bb[cur], wcol, lid, quad, bf_);
        #pragma unroll
        for (int i = 0; i < 4; ++i)
            #pragma unroll
            for (int j = 0; j < 4; ++j)
                acc[i][j] = mfma16(af[i], bf_[j], acc[i][j]);
        __syncthreads();
        cur ^= 1;
    }
    {
        short8 af[4], bf_[4];
        frag4_x32(Ab[cur], wrow, lid, quad, af);
        frag4_x32(Bb[cur], wcol, lid, quad, bf_);
        #pragma unroll
        for (int i = 0; i < 4; ++i)
            #pragma unroll
            for (int j = 0; j < 4; ++j)
                acc[i][j] = mfma16(af[i], bf_[j], acc[i][j]);
    }

    if (z == 2) {
        #pragma unroll
        for (int i = 0; i < 4; ++i) {
            const int rg = row0 + wrow + i * 16 + quad * 4;
            const int b  = rg >> 9;
            const int j  = rg & 511;
            #pragma unroll
            for (int jt = 0; jt < 4; ++jt) {
                const int col = col0 + wcol + jt * 16 + lid;
                *(ushort4*)(Vt + (size_t)b * DD * MM + (size_t)col * MM + j) =
                    make_ushort4(rne_bf16(acc[i][jt][0]), rne_bf16(acc[i][jt][1]),
                                 rne_bf16(acc[i][jt][2]), rne_bf16(acc[i][jt][3]));
            }
        }
    } else {
        unsigned short* dst = (z == 0) ? Qa : Kb;
        #pragma unroll
        for (int i = 0; i < 4; ++i) {
            const int rg = row0 + wrow + i * 16 + quad * 4;
            #pragma unroll
            for (int r = 0; r < 4; ++r) {
                unsigned short* rowp = dst + (size_t)(rg + r) * KS;
                #pragma unroll
                for (int jt = 0; jt < 4; ++jt) {
                    const int col = col0 + wcol + jt * 16 + lid;
                    const float v = acc[i][jt][r];
                    unsigned short h = rne_bf16(v);
                    rowp[col]       = h;                          // h-plane
                    rowp[256 + col] = rne_bf16(v - bf2f(h));      // l-plane
                }
            }
        }
    }
}

// ---------------------------------------------------------------------------
// FUSED self scores (x z<64, y z>=64): 64 rows x FULL 512 cols per block,
// k'=768 planar (24 windows, dbuf). In-kernel full-row softmax stats:
// writes raw masked S (fp32), P = exp(S - m) (bf16, for ctx), inv = 1/sum.
// grid = 576 (8 XCD x 9 z x 8 row-blocks), 256 threads (4 col-waves).
// ---------------------------------------------------------------------------
__global__ __launch_bounds__(256, 2) void scores_self_kernel(
    const unsigned short* __restrict__ Qa,
    const unsigned short* __restrict__ Kb,
    const int* __restrict__ mask_x, const int* __restrict__ mask_y,
    float* __restrict__ Sbase, unsigned short* __restrict__ P,
    float* __restrict__ inv_all)
{
    const int xcd = blockIdx.x & 7, idx = blockIdx.x >> 3;
    const int lin = xcd * 72 + idx;          // 576 = 8*72
    const int z    = lin >> 3;               // 0..71
    const int brow = (lin & 7) * 64;
    const unsigned short* Asrc = Qa + (size_t)(z * MM + brow) * KS;
    const unsigned short* Bsrc = Kb + (size_t)z * MM * KS;
    const int* msk = (z < 64) ? (mask_x + z * MM) : (mask_y + (z - 64) * MM);
    float* S = Sbase + (size_t)z * MM * MM;

    __shared__ unsigned short Ab[2][64][32];
    __shared__ unsigned short Bb[2][512][32];
    __shared__ float pm4[64][4], ps4[64][4], smx[64];

    const int t = threadIdx.x;
    const int wave = t >> 6, lane = t & 63, quad = lane >> 4, lid = lane & 15;
    const int wcol = wave * 128;

    f32x4 acc[4][8];
    #pragma unroll
    for (int i = 0; i < 4; ++i)
        #pragma unroll
        for (int j = 0; j < 8; ++j) acc[i][j] = (f32x4){0.f, 0.f, 0.f, 0.f};

    // LDS dst wave-uniform (HW adds lane*16); global src per-lane.
    auto stage = [&](int buf, int w) {
        {   // A: 64 rows x 4 chunks = 256 chunks, lane-ordered
            const int r = t >> 2, cin = (t & 3) ^ (r & 3);
            gld16(Asrc + (size_t)r * KS + awin32(w) + cin * 8,
                  &Ab[buf][0][0] + (size_t)(wave * 64) * 8);
        }
        const int bw = bwin32(w);
        #pragma unroll
        for (int k = 0; k < 8; ++k) {        // B: 512 rows x 4 chunks = 2048
            const int c = k * 256 + t;
            const int r = c >> 2, cin = (c & 3) ^ (r & 3);
            gld16(Bsrc + (size_t)r * KS + bw + cin * 8,
                  &Bb[buf][0][0] + (size_t)(k * 256 + wave * 64) * 8);
        }
    };
    auto comp = [&](int buf) {
        short8 af[4], bv[8];
        frag4_x32(Ab[buf], 0, lid, quad, af);
        frag4_x32(Bb[buf], wcol, lid, quad, bv);
        frag4_x32(Bb[buf], wcol + 64, lid, quad, bv + 4);
        #pragma unroll
        for (int i = 0; i < 4; ++i)
            #pragma unroll
            for (int j = 0; j < 8; ++j)
                acc[i][j] = mfma16(af[i], bv[j], acc[i][j]);
    };

    stage(0, 0);
    __syncthreads();
    int cur = 0;
    for (int w = 0; w < 23; ++w) {
        stage(cur ^ 1, w + 1);
        comp(cur);
        __syncthreads();
        cur ^= 1;
    }
    comp(cur);

    int mcol[8];
    #pragma unroll
    for (int j = 0; j < 8; ++j) mcol[j] = msk[wcol + j * 16 + lid];

    // pass 1: raw S writes + per-wave row partials
    #pragma unroll
    for (int i = 0; i < 4; ++i) {
        #pragma unroll
        for (int r = 0; r < 4; ++r) {
            const int rl = i * 16 + quad * 4 + r;
            const bool mr = (msk[brow + rl] != 0);
            float* Srow = S + (size_t)(brow + rl) * MM;
            float vv[8];
            float mt = -3.4e38f;
            #pragma unroll
            for (int j = 0; j < 8; ++j) {
                const int col = wcol + j * 16 + lid;
                const bool valid = mr && (mcol[j] != 0);
                vv[j] = valid ? acc[i][j][r] : NEG_FILL_F;
                Srow[col] = vv[j];
                mt = fmaxf(mt, vv[j]);
            }
            #pragma unroll
            for (int o = 1; o < 16; o <<= 1) mt = fmaxf(mt, __shfl_xor(mt, o));
            float se = 0.f;
            #pragma unroll
            for (int j = 0; j < 8; ++j) se += __expf(vv[j] - mt);
            #pragma unroll
            for (int o = 1; o < 16; o <<= 1) se += __shfl_xor(se, o);
            if (lid == 0) { pm4[rl][wave] = mt; ps4[rl][wave] = se; }
        }
    }
    __syncthreads();
    if (t < 64) {
        const float m = fmaxf(fmaxf(pm4[t][0], pm4[t][1]),
                              fmaxf(pm4[t][2], pm4[t][3]));
        float s = 0.f;
        #pragma unroll
        for (int c = 0; c < 4; ++c) s += ps4[t][c] * __expf(pm4[t][c] - m);
        smx[t] = m;
        inv_all[z * MM + brow + t] = 1.0f / s;   // all-masked: m=NEG, s=512
    }
    __syncthreads();
    // pass 2: P = exp(S - m) bf16 (exact values ctx's exp stage produced)
    #pragma unroll
    for (int i = 0; i < 4; ++i) {
        #pragma unroll
        for (int r = 0; r < 4; ++r) {
            const int rl = i * 16 + quad * 4 + r;
            const bool mr = (msk[brow + rl] != 0);
            const float m = smx[rl];
            unsigned short* Prow = P + (size_t)(z * MM + brow + rl) * KS;
            #pragma unroll
            for (int j = 0; j < 8; ++j) {
                const int col = wcol + j * 16 + lid;
                const bool valid = mr && (mcol[j] != 0);
                const float v = valid ? acc[i][j][r] : NEG_FILL_F;
                Prow[col] = rne_bf16(__expf(v - m));
            }
        }
    }
}

// ---------------------------------------------------------------------------
// FUSED cross scores (xy): 64 rows x full 512 cols, single bf16 K=256
// (h-plane), 8 windows dbuf. Writes FINAL probs (softmax fused, no raw S
// round-trip) + mask floats. grid = 512 (8 XCD x 8 zz s-major x 8 rb).
// ---------------------------------------------------------------------------
__global__ __launch_bounds__(256, 2) void scores_xy_kernel(
    const unsigned short* __restrict__ Qa, const unsigned short* __restrict__ Kb,
    const int* __restrict__ mask_x, const int* __restrict__ mask_y,
    float* __restrict__ Prb, float* __restrict__ Mb)
{
    const int xcd = blockIdx.x & 7, idx = blockIdx.x >> 3;
    const int lin = xcd * 64 + idx;          // 512 = 8*64
    const int zz = lin >> 3;                 // s-major
    const int brow = (lin & 7) * 64;
    const int s = zz >> 3, n = zz & 7;
    const int zo = n * 8 + s;                // output slot (reference order)
    const int bq = s * 8 + n;                // x batch
    const int bk = s;                        // y batch
    const unsigned short* Asrc = Qa + (size_t)(bq * MM + brow) * KS;
    const unsigned short* Bsrc = Kb + (size_t)(ROWS_X + bk * MM) * KS;
    const int* mq = mask_x + bq * MM;
    const int* mk = mask_y + bk * MM;
    float* Pl = Prb + (size_t)zo * MM * MM;
    float* Ml = Mb  + (size_t)zo * MM * MM;

    __shared__ unsigned short Ab[2][64][32];
    __shared__ unsigned short Bb[2][512][32];
    __shared__ float pm4[64][4], ps4[64][4], smx[64], sin[64];

    const int t = threadIdx.x;
    const int wave = t >> 6, lane = t & 63, quad = lane >> 4, lid = lane & 15;
    const int wcol = wave * 128;

    f32x4 acc[4][8];
    #pragma unroll
    for (int i = 0; i < 4; ++i)
        #pragma unroll
        for (int j = 0; j < 8; ++j) acc[i][j] = (f32x4){0.f, 0.f, 0.f, 0.f};

    auto stage = [&](int buf, int w) {
        {
            const int r = t >> 2, cin = (t & 3) ^ (r & 3);
            gld16(Asrc + (size_t)r * KS + w * 32 + cin * 8,
                  &Ab[buf][0][0] + (size_t)(wave * 64) * 8);
        }
        #pragma unroll
        for (int k = 0; k < 8; ++k) {
            const int c = k * 256 + t;
            const int r = c >> 2, cin = (c & 3) ^ (r & 3);
            gld16(Bsrc + (size_t)r * KS + w * 32 + cin * 8,
                  &Bb[buf][0][0] + (size_t)(k * 256 + wave * 64) * 8);
        }
    };
    auto comp = [&](int buf) {
        short8 af[4], bv[8];
        frag4_x32(Ab[buf], 0, lid, quad, af);
        frag4_x32(Bb[buf], wcol, lid, quad, bv);
        frag4_x32(Bb[buf], wcol + 64, lid, quad, bv + 4);
        #pragma unroll
        for (int i = 0; i < 4; ++i)
            #pragma unroll
            for (int j = 0; j < 8; ++j)
                acc[i][j] = mfma16(af[i], bv[j], acc[i][j]);
    };

    stage(0, 0);
    __syncthreads();
    int cur = 0;
    for (int w = 0; w < 7; ++w) {
        stage(cur ^ 1, w + 1);
        comp(cur);
        __syncthreads();
        cur ^= 1;
    }
    comp(cur);

    int mcol[8];
    #pragma unroll
    for (int j = 0; j < 8; ++j) mcol[j] = mk[wcol + j * 16 + lid];

    // pass 1: mask floats + partials
    #pragma unroll
    for (int i = 0; i < 4; ++i) {
        #pragma unroll
        for (int r = 0; r < 4; ++r) {
            const int rl = i * 16 + quad * 4 + r;
            const bool mr = (mq[brow + rl] != 0);
            float* Mrow = Ml + (size_t)(brow + rl) * MM;
            float vv[8];
            float mt = -3.4e38f;
            #pragma unroll
            for (int j = 0; j < 8; ++j) {
                const int col = wcol + j * 16 + lid;
                const bool valid = mr && (mcol[j] != 0);
                vv[j] = valid ? acc[i][j][r] : NEG_FILL_F;
                Mrow[col] = valid ? 1.0f : 0.0f;
                mt = fmaxf(mt, vv[j]);
            }
            #pragma unroll
            for (int o = 1; o < 16; o <<= 1) mt = fmaxf(mt, __shfl_xor(mt, o));
            float se = 0.f;
            #pragma unroll
            for (int j = 0; j < 8; ++j) se += __expf(vv[j] - mt);
            #pragma unroll
            for (int o = 1; o < 16; o <<= 1) se += __shfl_xor(se, o);
            if (lid == 0) { pm4[rl][wave] = mt; ps4[rl][wave] = se; }
        }
    }
    __syncthreads();
    if (t < 64) {
        const float m = fmaxf(fmaxf(pm4[t][0], pm4[t][1]),
                              fmaxf(pm4[t][2], pm4[t][3]));
        float ssum = 0.f;
        #pragma unroll
        for (int c = 0; c < 4; ++c) ssum += ps4[t][c] * __expf(pm4[t][c] - m);
        smx[t] = m;
        sin[t] = 1.0f / ssum;
    }
    __syncthreads();
    // pass 2: final probs (no raw-S write, no second kernel)
    #pragma unroll
    for (int i = 0; i < 4; ++i) {
        #pragma unroll
        for (int r = 0; r < 4; ++r) {
            const int rl = i * 16 + quad * 4 + r;
            const bool mr = (mq[brow + rl] != 0);
            const float m = smx[rl], iv = sin[rl];
            float* Prow = Pl + (size_t)(brow + rl) * MM;
            #pragma unroll
            for (int j = 0; j < 8; ++j) {
                const int col = wcol + j * 16 + lid;
                const bool valid = mr && (mcol[j] != 0);
                const float v = valid ? acc[i][j][r] : NEG_FILL_F;
                Prow[col] = __expf(v - m) * iv;
            }
        }
    }
}

// ---------------------------------------------------------------------------
// Context via MFMA: pure async-staged GEMM now. A = P (bf16 exp-probs,
// stride KS) async; B = Vt async. 64 rows x 256 cols per block, 16 windows
// dbuf, epilogue scales by inv. grid = 576 (8 XCD x 9 b x 8 rb), 256 thr.
// ---------------------------------------------------------------------------
__global__ __launch_bounds__(256) void ctx_kernel(
    const unsigned short* __restrict__ P, const float* __restrict__ inv_all,
    const unsigned short* __restrict__ Vt_base, float* __restrict__ Obase)
{
    const int xcd = blockIdx.x & 7, idx = blockIdx.x >> 3;
    const int lin = xcd * 72 + idx;          // 576 = 8*72
    const int b    = lin >> 3;
    const int brow = (lin & 7) * 64;
    const unsigned short* Psrc = P + (size_t)(b * MM + brow) * KS;
    const unsigned short* Vt   = Vt_base + (size_t)b * DD * MM;
    float*                O    = Obase + (size_t)b * MM * DD;
    const float*          iv   = inv_all + b * MM + brow;

    __shared__ unsigned short Ab[2][64][32];
    __shared__ unsigned short Bb[2][256][32];

    const int t = threadIdx.x;
    const int wave = t >> 6, lane = t & 63, quad = lane >> 4, lid = lane & 15;
    const int wcol = wave * 64;

    f32x4 acc[4][4];
    #pragma unroll
    for (int i = 0; i < 4; ++i)
        #pragma unroll
        for (int j = 0; j < 4; ++j) acc[i][j] = (f32x4){0.f, 0.f, 0.f, 0.f};

    auto stage = [&](int buf, int w) {
        {   // A: 64 rows x 4 chunks
            const int r = t >> 2, cin = (t & 3) ^ (r & 3);
            gld16(Psrc + (size_t)r * KS + w * 32 + cin * 8,
                  &Ab[buf][0][0] + (size_t)(wave * 64) * 8);
        }
        #pragma unroll
        for (int k = 0; k < 4; ++k) {   // B: 256 rows (d) x 4 chunks
            const int c = k * 256 + t;
            const int r = c >> 2, cin = (c & 3) ^ (r & 3);
            gld16(Vt + (size_t)r * MM + w * 32 + cin * 8,
                  &Bb[buf][0][0] + (size_t)(k * 256 + wave * 64) * 8);
        }
    };
    auto comp = [&](int buf) {
        short8 af[4], bf_[4];
        frag4_x32(Ab[buf], 0, lid, quad, af);
        frag4_x32(Bb[buf], wcol, lid, quad, bf_);
        #pragma unroll
        for (int i = 0; i < 4; ++i)
            #pragma unroll
            for (int j = 0; j < 4; ++j)
                acc[i][j] = mfma16(af[i], bf_[j], acc[i][j]);
    };

    stage(0, 0);
    __syncthreads();
    int cur = 0;
    for (int w = 0; w < 15; ++w) {
        stage(cur ^ 1, w + 1);
        comp(cur);
        __syncthreads();
        cur ^= 1;
    }
    comp(cur);

    #pragma unroll
    for (int i = 0; i < 4; ++i) {
        const int rl0 = i * 16 + quad * 4;
        float inv[4];
        #pragma unroll
        for (int r = 0; r < 4; ++r) inv[r] = iv[rl0 + r];
        #pragma unroll
        for (int jt = 0; jt < 4; ++jt) {
            const int col = wcol + jt * 16 + lid;
            #pragma unroll
            for (int r = 0; r < 4; ++r)
                O[(size_t)(brow + rl0 + r) * DD + col] = acc[i][jt][r] * inv[r];
        }
    }
}

// ---------------------------------------------------------------------------
// y_len: one block per s, 64-lane reduce of mask_y[s,:]; lane n<8 writes n*8+s.
// ---------------------------------------------------------------------------
__global__ void ylen_kernel(const int* __restrict__ mask_y, float* __restrict__ out)
{
    const int s = blockIdx.x;
    const int lane = threadIdx.x;
    int c = 0;
    #pragma unroll
    for (int k = 0; k < 8; ++k) c += (mask_y[s * MM + k * 64 + lane] != 0);
    #pragma unroll
    for (int off = 32; off; off >>= 1) c += __shfl_xor(c, off);
    if (lane < 8) out[lane * 8 + s] = (float)c;
}

// ---------------------------------------------------------------------------
extern "C" void kernel_launch(void* const* d_in, const int* in_sizes, int n_in,
                              void* d_out, int out_size, void* d_ws, size_t ws_size,
                              hipStream_t stream)
{
    const float* x      = (const float*)d_in[0];
    const float* y      = (const float*)d_in[1];
    const int*   mask_x = (const int*)d_in[2];
    const int*   mask_y = (const int*)d_in[3];
    const float* Wq     = (const float*)d_in[4];
    const float* Wk     = (const float*)d_in[5];
    const float* Wv     = (const float*)d_in[6];
    float* out = (float*)d_out;

    // Workspace (~133 MB): Wb | xs | Qa | Kb | Vt | inv
    unsigned short* Wb = (unsigned short*)d_ws;            // 3*256*512   = 393216
    unsigned short* xs = Wb + 393216;                      // 36864*512   = 18874368
    unsigned short* Qa = xs + 18874368;
    unsigned short* Kb = Qa + 18874368;
    unsigned short* Vt = Kb + 18874368;                    // 72*256*512  = 9437184
    float* inv_all = (float*)(Vt + 9437184);               // 36864 floats

    // Output slots (floats, concatenated in reference return order)
    float* out_ctx   = out;                 // 64*512*256 + 8*512*256
    float* out_sx    = out + 9437184;       // 64*512*512 (+sy)
    float* out_pxy   = out + 28311552;      // 8*8*512*512
    float* out_mxy   = out + 45088768;      // 8*8*512*512
    float* out_ylen  = out + 61865984;      // 8*8

    // P (bf16 [36864][512], 37.7MB) lives in out_pxy scratch: produced by
    // scores_self, consumed by ctx, then pxy overwritten by scores_xy.
    unsigned short* P = (unsigned short*)out_pxy;

    // 1. splits + y_len
    convw_kernel<<<96, 256, 0, stream>>>(Wq, Wk, Wv, Wb);
    convx_kernel<<<4608, 256, 0, stream>>>(x, y, xs);
    ylen_kernel<<<8, 64, 0, stream>>>(mask_y, out_ylen);

    // 2. Projections
    proj_kernel<<<1728, 256, 0, stream>>>(xs, Wb, Qa, Kb, Vt);

    // 3. Self scores (fused softmax stats -> S, P, inv)
    scores_self_kernel<<<576, 256, 0, stream>>>(
        Qa, Kb, mask_x, mask_y, out_sx, P, inv_all);

    // 4. Context (reads P before xy overwrites the region)
    ctx_kernel<<<576, 256, 0, stream>>>(P, inv_all, Vt, out_ctx);

    // 5. Cross scores (fused softmax -> final probs + mask)
    scores_xy_kernel<<<512, 256, 0, stream>>>(
        Qa, Kb, mask_x, mask_y, out_pxy, out_mxy);
}